// Round 10
// baseline (7003.458 us; speedup 1.0000x reference)
//
#include <hip/hip_runtime.h>
#include <stdint.h>

// LSTM forward, B=32 T=2048 D=512 H=512 G=2048.
// Round 10 = round 9 (gate-interleaved in-wave elem, 2 barriers, no Gt2)
// with the store-ack hazard removed:
//   per-step wave FIFO = [gxn][pollA][pub][out x3]; check = VMWAIT(4)
//   -> retires gxn+pollA only, never waits pub/out acks (they retire
//   lazily under the NEXT step's VMWAIT(4), by then ~1 step old).
//   pollA may legally precede pub because own-WG columns are self-injected
//   through LDS: owner lanes ds_write_b16 their h into As after barrier B;
//   the 8 threads/row whose poll dwords are own-cols skip the tag check.
// Exchange: tagged dwords (lo16 bf16 h | hi16 step), double-buffered slots,
// all sc0sc1 (MALL). Tag+payload share a dword => no fences.

#define B_ 32
#define T_ 2048
#define D_ 512
#define H_ 512
#define G_ 2048
#define NCG 16
#define NBG 8

typedef __attribute__((ext_vector_type(4))) float f32x4;
typedef __attribute__((ext_vector_type(8))) short bf16x8;
typedef __attribute__((ext_vector_type(4))) unsigned int uint4v;
typedef __attribute__((ext_vector_type(2))) unsigned int uint2v;

__device__ __forceinline__ unsigned short f2bf(float f) {
  union { float f; unsigned int u; } v; v.f = f;
  unsigned int r = (v.u + 0x7FFFu + ((v.u >> 16) & 1u)) >> 16;
  return (unsigned short)r;
}
__device__ __forceinline__ float bf2f(unsigned short s) {
  union { unsigned int u; float f; } v; v.u = ((unsigned int)s) << 16;
  return v.f;
}
__device__ __forceinline__ float sigm(float x) { return 1.0f / (1.0f + __expf(-x)); }
__device__ __forceinline__ float tanh_(float x) { return 1.0f - 2.0f / (__expf(2.0f * x) + 1.0f); }

__device__ __forceinline__ void store_x4_coherent(unsigned int* p, uint4v v) {
  asm volatile("global_store_dwordx4 %0, %1, off sc0 sc1" :: "v"(p), "v"(v) : "memory");
}

#define BARRIER_LGKM()                                          \
  do {                                                          \
    asm volatile("s_waitcnt lgkmcnt(0)" ::: "memory");          \
    __builtin_amdgcn_sched_barrier(0);                          \
    __builtin_amdgcn_s_barrier();                               \
    __builtin_amdgcn_sched_barrier(0);                          \
  } while (0)

#define VMWAIT(N)                                               \
  do { asm volatile("s_waitcnt vmcnt(" #N ")" ::: "memory");    \
       __builtin_amdgcn_sched_barrier(0); } while (0)

// ---------------- Phase 1: convert inputs + seed/clear h_tag ----------------
__global__ __launch_bounds__(256) void prep_kernel(
    const float* __restrict__ x, const float* __restrict__ w_ih,
    const float* __restrict__ hx,
    unsigned short* __restrict__ x_bf, unsigned short* __restrict__ w_bf,
    unsigned int* __restrict__ h_tag) {
  const int NX8 = (B_ * T_ * D_) / 8;   // 4,194,304
  const int NWT8 = (G_ * D_) / 8;       // 131,072
  int i = blockIdx.x * 256 + threadIdx.x;
  if (i < NX8) {
    float4 a = reinterpret_cast<const float4*>(x)[i * 2];
    float4 b = reinterpret_cast<const float4*>(x)[i * 2 + 1];
    uint4v v;
    v[0] = (unsigned)f2bf(a.x) | ((unsigned)f2bf(a.y) << 16);
    v[1] = (unsigned)f2bf(a.z) | ((unsigned)f2bf(a.w) << 16);
    v[2] = (unsigned)f2bf(b.x) | ((unsigned)f2bf(b.y) << 16);
    v[3] = (unsigned)f2bf(b.z) | ((unsigned)f2bf(b.w) << 16);
    reinterpret_cast<uint4v*>(x_bf)[i] = v;
  } else if (i < NX8 + NWT8) {
    int j = i - NX8;
    float4 a = reinterpret_cast<const float4*>(w_ih)[j * 2];
    float4 b = reinterpret_cast<const float4*>(w_ih)[j * 2 + 1];
    uint4v v;
    v[0] = (unsigned)f2bf(a.x) | ((unsigned)f2bf(a.y) << 16);
    v[1] = (unsigned)f2bf(a.z) | ((unsigned)f2bf(a.w) << 16);
    v[2] = (unsigned)f2bf(b.x) | ((unsigned)f2bf(b.y) << 16);
    v[3] = (unsigned)f2bf(b.z) | ((unsigned)f2bf(b.w) << 16);
    reinterpret_cast<uint4v*>(w_bf)[j] = v;
  } else if (i < NX8 + NWT8 + 2048) {
    int j = i - NX8 - NWT8;  // seed slot 0 from hx, tag 0
    float4 a = reinterpret_cast<const float4*>(hx)[j * 2];
    float4 b = reinterpret_cast<const float4*>(hx)[j * 2 + 1];
    uint4v v0, v1;
    v0[0] = f2bf(a.x); v0[1] = f2bf(a.y); v0[2] = f2bf(a.z); v0[3] = f2bf(a.w);
    v1[0] = f2bf(b.x); v1[1] = f2bf(b.y); v1[2] = f2bf(b.z); v1[3] = f2bf(b.w);
    unsigned int* p = h_tag + j * 8;
    store_x4_coherent(p, v0);
    store_x4_coherent(p + 4, v1);
  } else {
    int j = i - NX8 - NWT8 - 2048;  // clear slot 1
    unsigned int* p = h_tag + 16384 + j * 8;
    uint4v z = {0u, 0u, 0u, 0u};
    store_x4_coherent(p, z);
    store_x4_coherent(p + 4, z);
  }
}

// ---------------- Phase 2: gx GEMM (unchanged) ----------------
__global__ __launch_bounds__(256, 2) void gemm_gx(
    const unsigned short* __restrict__ x_bf, const unsigned short* __restrict__ w_bf,
    const float* __restrict__ b_ih, const float* __restrict__ b_hh,
    unsigned short* __restrict__ gx_ws) {
  __shared__ unsigned short As[128 * 40];
  __shared__ unsigned short Bs[128 * 40];
  __shared__ unsigned short Eg[128 * 136];
  const int bid = blockIdx.x;
  const int cb = bid & 15, rb = bid >> 4;
  const int r0 = rb * 128, c0 = cb * 128;
  const int tid = threadIdx.x;
  const int lane = tid & 63;
  const int w = tid >> 6;
  const int qr = (w >> 1) * 64, qc = (w & 1) * 64;
  f32x4 acc[4][4] = {};

  for (int kt = 0; kt < 16; ++kt) {
    const int k0 = kt * 32;
    uint4v av[2], bv[2];
#pragma unroll
    for (int c = 0; c < 2; ++c) {
      int flat = c * 256 + tid;
      int row = flat >> 2, q = flat & 3;
      av[c] = *reinterpret_cast<const uint4v*>(x_bf + (size_t)(r0 + row) * 512 + k0 + q * 8);
      bv[c] = *reinterpret_cast<const uint4v*>(w_bf + (size_t)(c0 + row) * 512 + k0 + q * 8);
    }
    __syncthreads();
#pragma unroll
    for (int c = 0; c < 2; ++c) {
      int flat = c * 256 + tid;
      int row = flat >> 2, q = flat & 3;
      *reinterpret_cast<uint4v*>(&As[row * 40 + q * 8]) = av[c];
      *reinterpret_cast<uint4v*>(&Bs[row * 40 + q * 8]) = bv[c];
    }
    __syncthreads();
    bf16x8 af[4], bfr[4];
#pragma unroll
    for (int mt = 0; mt < 4; ++mt)
      af[mt] = *reinterpret_cast<const bf16x8*>(&As[(qr + mt * 16 + (lane & 15)) * 40 + (lane >> 4) * 8]);
#pragma unroll
    for (int nt = 0; nt < 4; ++nt)
      bfr[nt] = *reinterpret_cast<const bf16x8*>(&Bs[(qc + nt * 16 + (lane & 15)) * 40 + (lane >> 4) * 8]);
#pragma unroll
    for (int mt = 0; mt < 4; ++mt)
#pragma unroll
      for (int nt = 0; nt < 4; ++nt)
        acc[mt][nt] = __builtin_amdgcn_mfma_f32_16x16x32_bf16(af[mt], bfr[nt], acc[mt][nt], 0, 0, 0);
  }
  __syncthreads();
#pragma unroll
  for (int nt = 0; nt < 4; ++nt) {
    int cg = c0 + qc + nt * 16 + (lane & 15);
    float bias = b_ih[cg] + b_hh[cg];
#pragma unroll
    for (int mt = 0; mt < 4; ++mt)
#pragma unroll
      for (int j = 0; j < 4; ++j) {
        int tr = qr + mt * 16 + (lane >> 4) * 4 + j;
        int cl = qc + nt * 16 + (lane & 15);
        Eg[tr * 136 + cl] = f2bf(acc[mt][nt][j] + bias);
      }
  }
  __syncthreads();
  const int b = r0 >> 11;
  const int g = c0 >> 9;
  const int t0 = r0 & 2047;
  const int nw0 = (c0 & 511) >> 5;
  const int bg = b >> 2, bq = b & 3;
  for (int c = tid; c < 512; c += 256) {
    int tr = c >> 2, nwi = c & 3;
    size_t dst = (((size_t)(t0 + tr) * NBG + bg) * NCG + (nw0 + nwi)) * 512 + bq * 128 + g * 32;
    const unsigned short* src = &Eg[tr * 136 + nwi * 32];
#pragma unroll
    for (int q = 0; q < 4; ++q)
      *reinterpret_cast<uint4v*>(gx_ws + dst + q * 8) =
          *reinterpret_cast<const uint4v*>(src + q * 8);
  }
}

// ---------------- Phase 3: recurrence ----------------
#define POLLQ(PP) \
  asm volatile("global_load_dwordx4 %0, %1, off sc0 sc1" : "=v"(hv) : "v"(PP))

#define SPIN4(PP, WANT)                                                         \
  do {                                                                          \
    unsigned want_ = (unsigned)(WANT);                                          \
    unsigned bad_ = ((hv[0] >> 16) ^ want_) | ((hv[1] >> 16) ^ want_) |         \
                    ((hv[2] >> 16) ^ want_) | ((hv[3] >> 16) ^ want_);          \
    int guard_ = 0;                                                             \
    while (bad_) {                                                              \
      POLLQ(PP);                                                                \
      VMWAIT(0);                                                                \
      bad_ = ((hv[0] >> 16) ^ want_) | ((hv[1] >> 16) ^ want_) |                \
             ((hv[2] >> 16) ^ want_) | ((hv[3] >> 16) ^ want_);                 \
      if (++guard_ > (1 << 20)) break;                                          \
    }                                                                           \
  } while (0)

#define UNPACK_AS()                                                             \
  do {                                                                          \
    uint2v pk_;                                                                 \
    pk_[0] = (hv[0] & 0xffffu) | (hv[1] << 16);                                 \
    pk_[1] = (hv[2] & 0xffffu) | (hv[3] << 16);                                 \
    *reinterpret_cast<uint2v*>(&As[(tid >> 7) * 536 + (tid & 127) * 4]) = pk_;  \
  } while (0)

__global__ __launch_bounds__(512) void lstm_rec(
    const float* __restrict__ cx, const float* __restrict__ w_hh,
    const unsigned short* __restrict__ gx_ws, unsigned int* __restrict__ h_tag,
    float* __restrict__ out) {
  const int bid = blockIdx.x;
  const int bg = bid & 7;    // batch-group (domain)
  const int nw = bid >> 3;   // col-group: h-cols [nw*32, +32)
  const int tid = threadIdx.x;
  const int lane = tid & 63;
  const int w = tid >> 6;
  const int rg = lane >> 4;        // batch owned by this lane's row-group
  const int g4 = (lane >> 2) & 3;  // gate type of this lane's N-col
  const int cq = lane & 3;         // col-in-wave
  const bool owner = (g4 == 0);
  const bool ownq = (((tid & 127) >> 3) == nw);  // poll dwords are own cols
  const int col = nw * 32 + w * 4 + cq;
  __shared__ unsigned short As[4 * 536];   // h rows (bf16), stride 536

  // B-frags: N-tile = {i,f,g,o} x 4 cols, full K=512 -> 16 frags = 64 VGPR
  bf16x8 breg[16];
  {
    int gcol = g4 * 512 + col;
    const float* wrow = w_hh + (size_t)gcol * 512;
#pragma unroll
    for (int kk = 0; kk < 16; ++kk) {
      int k = kk * 32 + (lane >> 4) * 8;
      float4 f0 = *reinterpret_cast<const float4*>(wrow + k);
      float4 f1 = *reinterpret_cast<const float4*>(wrow + k + 4);
      uint4v v;
      v[0] = (unsigned)f2bf(f0.x) | ((unsigned)f2bf(f0.y) << 16);
      v[1] = (unsigned)f2bf(f0.z) | ((unsigned)f2bf(f0.w) << 16);
      v[2] = (unsigned)f2bf(f1.x) | ((unsigned)f2bf(f1.y) << 16);
      v[3] = (unsigned)f2bf(f1.z) | ((unsigned)f2bf(f1.w) << 16);
      breg[kk] = __builtin_bit_cast(bf16x8, v);
    }
  }
  const int bno = bg * 4 + rg;
  float c = 0.0f;
  if (owner) {
    c = cx[bno * 512 + col];
    asm volatile("" :: "v"(c));
  }

  unsigned int* slot0 = h_tag;
  unsigned int* slot1 = h_tag + 16384;
  const unsigned int* pollp0 = slot0 + bg * 2048 + tid * 4;
  const unsigned int* pollp1 = slot1 + bg * 2048 + tid * 4;
  unsigned int* pub0 = slot0 + bno * 512 + col;
  unsigned int* pub1 = slot1 + bno * 512 + col;
  const unsigned short* gx_lane =
      gx_ws + ((size_t)bg * NCG + nw) * 512 + rg * 128 + g4 * 32 + (w * 4 + cq);
  const size_t GXT = (size_t)NBG * NCG * 512;  // elements per t
  const size_t BTH = (size_t)B_ * T_ * H_;

  uint4v hv;
  unsigned int gxr = 0, gxn = 0;

  // ---- prologue: gx(0) + full poll t=0 (tags seeded 0) + unpack (all)
  asm volatile("global_load_ushort %0, %1, off" : "=v"(gxr) : "v"(gx_lane));
  POLLQ(pollp0);
  VMWAIT(0);
  SPIN4(pollp0, 0u);
  UNPACK_AS();

  for (int t = 0; t < T_; ++t) {
    BARRIER_LGKM();  // As(t) ready (remote unpack + owner inject)
    const bool more = (t + 1 < T_);
    if (more)
      asm volatile("global_load_ushort %0, %1, off"
                   : "=v"(gxn) : "v"(gx_lane + (size_t)(t + 1) * GXT));
    // ---- MFMA: full K=512, gate-interleaved N-tile; 2 independent chains
    f32x4 a0 = {}, a1 = {};
#pragma unroll
    for (int kk = 0; kk < 16; kk += 2) {
      bf16x8 af0 = *reinterpret_cast<const bf16x8*>(
          &As[(lane & 3) * 536 + kk * 32 + (lane >> 4) * 8]);
      bf16x8 af1 = *reinterpret_cast<const bf16x8*>(
          &As[(lane & 3) * 536 + (kk + 1) * 32 + (lane >> 4) * 8]);
      a0 = __builtin_amdgcn_mfma_f32_16x16x32_bf16(af0, breg[kk], a0, 0, 0, 0);
      a1 = __builtin_amdgcn_mfma_f32_16x16x32_bf16(af1, breg[kk + 1], a1, 0, 0, 0);
    }
    f32x4 s4 = a0 + a1;  // acc[j] = batch j (A rows duplicated mod 4)
    // ---- in-wave elementwise (all 64 lanes)
    float sel = s4[0];
    sel = (rg == 1) ? s4[1] : sel;
    sel = (rg == 2) ? s4[2] : sel;
    sel = (rg == 3) ? s4[3] : sel;
    float s = sel + bf2f((unsigned short)gxr);
    const bool isg = (g4 == 2);
    float xin = isg ? 2.0f * s : s;            // tanh(s) = 2*sigm(2s)-1
    float u = 1.0f / (1.0f + __expf(-xin));
    float act = isg ? 2.0f * u - 1.0f : u;     // i/f/o: sigm; g: tanh
    int ai = __builtin_bit_cast(int, act);
    float fv = __builtin_bit_cast(float, __builtin_amdgcn_ds_swizzle(ai, 0x101F)); // lane^4: f
    float gv = __builtin_bit_cast(float, __builtin_amdgcn_ds_swizzle(ai, 0x201F)); // lane^8: g
    float ov = __builtin_bit_cast(float, __builtin_amdgcn_ds_swizzle(ai, 0x301F)); // lane^12: o
    float h = 0.0f;
    if (owner) {
      c = fv * c + act * gv;
      h = ov * tanh_(c);
    }
    // ---- issue order (per-wave FIFO): pollA, pub, out x3
    const unsigned int* pollp = ((t + 1) & 1) ? pollp1 : pollp0;
    if (more) POLLQ(pollp);  // pollA: before pub -> check never waits acks
    if (more && owner) {
      unsigned int word = (unsigned int)f2bf(h) | (((unsigned int)(t + 1)) << 16);
      unsigned int* q_ = ((t + 1) & 1) ? pub1 : pub0;
      asm volatile("global_store_dword %0, %1, off sc0 sc1" :: "v"(q_), "v"(word) : "memory");
    }
    if (owner) {
      size_t bo = (size_t)bno * (T_ * H_) + (size_t)t * H_ + col;
      const float* pf = out + bo;
      const float* ph = out + BTH + bo;
      const float* pg = out + 2 * BTH + bo;
      asm volatile("global_store_dword %0, %1, off" :: "v"(pf), "v"(fv) : "memory");
      asm volatile("global_store_dword %0, %1, off" :: "v"(ph), "v"(h) : "memory");
      asm volatile("global_store_dword %0, %1, off" :: "v"(pg), "v"(gv) : "memory");
      if (!more) {
        const float* po = out + 3 * BTH + (size_t)bno * H_ + col;
        asm volatile("global_store_dword %0, %1, off" :: "v"(po), "v"(ov) : "memory");
      }
    }
    BARRIER_LGKM();  // all As(t) reads complete -> safe to overwrite
    if (more) {
      if (owner) As[rg * 536 + col] = f2bf(h);  // self-inject own h(t)
      // FIFO: [gxn][pollA][pub][o][o][o] (+retired older) -> VMWAIT(4)
      // retires gxn + pollA WITHOUT waiting pub/out acks.
      VMWAIT(4);
      if (!ownq) {      // own-region threads: data comes via LDS inject
        SPIN4(pollp, t + 1);
        UNPACK_AS();
      }
      gxr = gxn;
    }
  }
}

extern "C" void kernel_launch(void* const* d_in, const int* in_sizes, int n_in,
                              void* d_out, int out_size, void* d_ws, size_t ws_size,
                              hipStream_t stream) {
  const float* x    = (const float*)d_in[0];
  const float* hx   = (const float*)d_in[1];
  const float* cx   = (const float*)d_in[2];
  const float* w_ih = (const float*)d_in[3];
  const float* w_hh = (const float*)d_in[4];
  const float* b_ih = (const float*)d_in[5];
  const float* b_hh = (const float*)d_in[6];
  float* out = (float*)d_out;
  char* ws = (char*)d_ws;
  const size_t OFF_XBF  = 0;                    // 67,108,864
  const size_t OFF_WBF  = 67108864;             //  2,097,152
  const size_t OFF_GX   = 69206016;             // 268,435,456
  const size_t OFF_HTAG = 337641472;            //    131,072
  const size_t NEEDED   = 337772544;
  if (ws_size < NEEDED) return;

  unsigned short* x_bf  = (unsigned short*)(ws + OFF_XBF);
  unsigned short* w_bf  = (unsigned short*)(ws + OFF_WBF);
  unsigned short* gx_ws = (unsigned short*)(ws + OFF_GX);
  unsigned int*   h_tag = (unsigned int*)(ws + OFF_HTAG);

  prep_kernel<<<16912, 256, 0, stream>>>(x, w_ih, hx, x_bf, w_bf, h_tag);
  gemm_gx<<<8192, 256, 0, stream>>>(x_bf, w_bf, b_ih, b_hh, gx_ws);
  lstm_rec<<<128, 512, 0, stream>>>(cx, w_hh, gx_ws, h_tag, out);
}

// Round 11
// 6140.081 us; speedup vs baseline: 1.1406x; 1.1406x over previous
//
#include <hip/hip_runtime.h>
#include <stdint.h>

// LSTM forward, B=32 T=2048 D=512 H=512 G=2048.
// Round 11 = round 6 structure (best so far, 5.12ms) with:
//   (1) NCG 16 -> 8: 64 WGs, 64 h-cols each (128 VGPR weights). Producers
//       per domain 16 -> 8 (skew max-of-8), WG count halved (less MALL
//       contention), publish/out chunks unchanged (64B per wave-row).
//   (2) Non-elem waves delay their first poll by s_sleep(5) (~320cy) so the
//       return lands after publishes are visible (kills the guaranteed-stale
//       first round -> detection in ~1 RTT instead of 2).
// Exchange protocol: tagged dwords (lo16 bf16 h | hi16 step), double-buffered
// slots, ALL sc0sc1 (MALL). Tag+payload share a dword => no fences needed.
// r8-r10 lessons kept: no dual publish, no sc0 fast path, no gate-interleave.

#define B_ 32
#define T_ 2048
#define D_ 512
#define H_ 512
#define G_ 2048
#define NCG 8
#define NBG 8

typedef __attribute__((ext_vector_type(4))) float f32x4;
typedef __attribute__((ext_vector_type(8))) short bf16x8;
typedef __attribute__((ext_vector_type(4))) unsigned int uint4v;
typedef __attribute__((ext_vector_type(2))) unsigned int uint2v;

__device__ __forceinline__ unsigned short f2bf(float f) {
  union { float f; unsigned int u; } v; v.f = f;
  unsigned int r = (v.u + 0x7FFFu + ((v.u >> 16) & 1u)) >> 16;
  return (unsigned short)r;
}
__device__ __forceinline__ float bf2f(unsigned short s) {
  union { unsigned int u; float f; } v; v.u = ((unsigned int)s) << 16;
  return v.f;
}
__device__ __forceinline__ float sigm(float x) { return 1.0f / (1.0f + __expf(-x)); }
__device__ __forceinline__ float tanh_(float x) { return 1.0f - 2.0f / (__expf(2.0f * x) + 1.0f); }

__device__ __forceinline__ void store_x4_coherent(unsigned int* p, uint4v v) {
  asm volatile("global_store_dwordx4 %0, %1, off sc0 sc1" :: "v"(p), "v"(v) : "memory");
}

#define BARRIER_LGKM()                                          \
  do {                                                          \
    asm volatile("s_waitcnt lgkmcnt(0)" ::: "memory");          \
    __builtin_amdgcn_sched_barrier(0);                          \
    __builtin_amdgcn_s_barrier();                               \
    __builtin_amdgcn_sched_barrier(0);                          \
  } while (0)

#define VMWAIT(N)                                               \
  do { asm volatile("s_waitcnt vmcnt(" #N ")" ::: "memory");    \
       __builtin_amdgcn_sched_barrier(0); } while (0)

// ---------------- Phase 1: convert inputs + seed/clear h_tag ----------------
__global__ __launch_bounds__(256) void prep_kernel(
    const float* __restrict__ x, const float* __restrict__ w_ih,
    const float* __restrict__ hx,
    unsigned short* __restrict__ x_bf, unsigned short* __restrict__ w_bf,
    unsigned int* __restrict__ h_tag) {
  const int NX8 = (B_ * T_ * D_) / 8;   // 4,194,304
  const int NWT8 = (G_ * D_) / 8;       // 131,072
  int i = blockIdx.x * 256 + threadIdx.x;
  if (i < NX8) {
    float4 a = reinterpret_cast<const float4*>(x)[i * 2];
    float4 b = reinterpret_cast<const float4*>(x)[i * 2 + 1];
    uint4v v;
    v[0] = (unsigned)f2bf(a.x) | ((unsigned)f2bf(a.y) << 16);
    v[1] = (unsigned)f2bf(a.z) | ((unsigned)f2bf(a.w) << 16);
    v[2] = (unsigned)f2bf(b.x) | ((unsigned)f2bf(b.y) << 16);
    v[3] = (unsigned)f2bf(b.z) | ((unsigned)f2bf(b.w) << 16);
    reinterpret_cast<uint4v*>(x_bf)[i] = v;
  } else if (i < NX8 + NWT8) {
    int j = i - NX8;
    float4 a = reinterpret_cast<const float4*>(w_ih)[j * 2];
    float4 b = reinterpret_cast<const float4*>(w_ih)[j * 2 + 1];
    uint4v v;
    v[0] = (unsigned)f2bf(a.x) | ((unsigned)f2bf(a.y) << 16);
    v[1] = (unsigned)f2bf(a.z) | ((unsigned)f2bf(a.w) << 16);
    v[2] = (unsigned)f2bf(b.x) | ((unsigned)f2bf(b.y) << 16);
    v[3] = (unsigned)f2bf(b.z) | ((unsigned)f2bf(b.w) << 16);
    reinterpret_cast<uint4v*>(w_bf)[j] = v;
  } else if (i < NX8 + NWT8 + 2048) {
    int j = i - NX8 - NWT8;  // seed slot 0 from hx, tag 0
    float4 a = reinterpret_cast<const float4*>(hx)[j * 2];
    float4 b = reinterpret_cast<const float4*>(hx)[j * 2 + 1];
    uint4v v0, v1;
    v0[0] = f2bf(a.x); v0[1] = f2bf(a.y); v0[2] = f2bf(a.z); v0[3] = f2bf(a.w);
    v1[0] = f2bf(b.x); v1[1] = f2bf(b.y); v1[2] = f2bf(b.z); v1[3] = f2bf(b.w);
    unsigned int* p = h_tag + j * 8;
    store_x4_coherent(p, v0);
    store_x4_coherent(p + 4, v1);
  } else {
    int j = i - NX8 - NWT8 - 2048;  // clear slot 1
    unsigned int* p = h_tag + 16384 + j * 8;
    uint4v z = {0u, 0u, 0u, 0u};
    store_x4_coherent(p, z);
    store_x4_coherent(p + 4, z);
  }
}

// ---------------- Phase 2: gx GEMM ----------------
// 128x128 tile over rows r=b*2048+t, cols gcol. Epilogue writes per-(t,bg,nw)
// blocks of 1024 bf16: [bq(4)][g(4)][jl(64)].
__global__ __launch_bounds__(256, 2) void gemm_gx(
    const unsigned short* __restrict__ x_bf, const unsigned short* __restrict__ w_bf,
    const float* __restrict__ b_ih, const float* __restrict__ b_hh,
    unsigned short* __restrict__ gx_ws) {
  __shared__ unsigned short As[128 * 40];
  __shared__ unsigned short Bs[128 * 40];
  __shared__ unsigned short Eg[128 * 136];
  const int bid = blockIdx.x;
  const int cb = bid & 15, rb = bid >> 4;
  const int r0 = rb * 128, c0 = cb * 128;
  const int tid = threadIdx.x;
  const int lane = tid & 63;
  const int w = tid >> 6;
  const int qr = (w >> 1) * 64, qc = (w & 1) * 64;
  f32x4 acc[4][4] = {};

  for (int kt = 0; kt < 16; ++kt) {
    const int k0 = kt * 32;
    uint4v av[2], bv[2];
#pragma unroll
    for (int c = 0; c < 2; ++c) {
      int flat = c * 256 + tid;
      int row = flat >> 2, q = flat & 3;
      av[c] = *reinterpret_cast<const uint4v*>(x_bf + (size_t)(r0 + row) * 512 + k0 + q * 8);
      bv[c] = *reinterpret_cast<const uint4v*>(w_bf + (size_t)(c0 + row) * 512 + k0 + q * 8);
    }
    __syncthreads();
#pragma unroll
    for (int c = 0; c < 2; ++c) {
      int flat = c * 256 + tid;
      int row = flat >> 2, q = flat & 3;
      *reinterpret_cast<uint4v*>(&As[row * 40 + q * 8]) = av[c];
      *reinterpret_cast<uint4v*>(&Bs[row * 40 + q * 8]) = bv[c];
    }
    __syncthreads();
    bf16x8 af[4], bfr[4];
#pragma unroll
    for (int mt = 0; mt < 4; ++mt)
      af[mt] = *reinterpret_cast<const bf16x8*>(&As[(qr + mt * 16 + (lane & 15)) * 40 + (lane >> 4) * 8]);
#pragma unroll
    for (int nt = 0; nt < 4; ++nt)
      bfr[nt] = *reinterpret_cast<const bf16x8*>(&Bs[(qc + nt * 16 + (lane & 15)) * 40 + (lane >> 4) * 8]);
#pragma unroll
    for (int mt = 0; mt < 4; ++mt)
#pragma unroll
      for (int nt = 0; nt < 4; ++nt)
        acc[mt][nt] = __builtin_amdgcn_mfma_f32_16x16x32_bf16(af[mt], bfr[nt], acc[mt][nt], 0, 0, 0);
  }
  __syncthreads();
#pragma unroll
  for (int nt = 0; nt < 4; ++nt) {
    int cg = c0 + qc + nt * 16 + (lane & 15);
    float bias = b_ih[cg] + b_hh[cg];
#pragma unroll
    for (int mt = 0; mt < 4; ++mt)
#pragma unroll
      for (int j = 0; j < 4; ++j) {
        int tr = qr + mt * 16 + (lane >> 4) * 4 + j;
        int cl = qc + nt * 16 + (lane & 15);
        Eg[tr * 136 + cl] = f2bf(acc[mt][nt][j] + bias);
      }
  }
  __syncthreads();
  const int b = r0 >> 11;          // batch, constant per tile
  const int g = c0 >> 9;           // gate, constant per tile
  const int t0 = r0 & 2047;
  const int nw0 = (c0 & 511) >> 6; // 2 col-groups per tile (64 cols each)
  const int bg = b >> 2, bq = b & 3;
  for (int c = tid; c < 2048; c += 256) {
    int tr = c >> 4;        // row 0..127
    int rem = c & 15;
    int nwi = rem >> 3;     // 0..1
    int q = rem & 7;        // 8 x uint4v per 64 cols
    size_t dst = (((size_t)(t0 + tr) * NBG + bg) * NCG + (nw0 + nwi)) * 1024
                 + bq * 256 + g * 64 + q * 8;
    *reinterpret_cast<uint4v*>(gx_ws + dst) =
        *reinterpret_cast<const uint4v*>(&Eg[tr * 136 + nwi * 64 + q * 8]);
  }
}

// ---------------- Phase 3: recurrence ----------------
// 64 WGs x 512 threads. WG (bg=bid&7, nw=bid>>3): h-cols [nw*64,+64),
// batches [bg*4,+4). Wave w owns 2 N-tiles (32 gate-cols), full K=512.
// Slot: [s][batch(32)][512] dwords (lo16 bf16 h | hi16 tag).
#define POLLQ(PP) \
  asm volatile("global_load_dwordx4 %0, %1, off sc0 sc1" : "=v"(hv) : "v"(PP))

#define SPIN4(PP, WANT)                                                         \
  do {                                                                          \
    unsigned want_ = (unsigned)(WANT);                                          \
    unsigned bad_ = ((hv[0] >> 16) ^ want_) | ((hv[1] >> 16) ^ want_) |         \
                    ((hv[2] >> 16) ^ want_) | ((hv[3] >> 16) ^ want_);          \
    int guard_ = 0;                                                             \
    while (bad_) {                                                              \
      POLLQ(PP);                                                                \
      VMWAIT(0);                                                                \
      bad_ = ((hv[0] >> 16) ^ want_) | ((hv[1] >> 16) ^ want_) |                \
             ((hv[2] >> 16) ^ want_) | ((hv[3] >> 16) ^ want_);                 \
      if (++guard_ > (1 << 20)) break;                                          \
    }                                                                           \
  } while (0)

#define UNPACK_AS()                                                             \
  do {                                                                          \
    uint2v pk_;                                                                 \
    pk_[0] = (hv[0] & 0xffffu) | (hv[1] << 16);                                 \
    pk_[1] = (hv[2] & 0xffffu) | (hv[3] << 16);                                 \
    *reinterpret_cast<uint2v*>(&As[(tid >> 7) * 536 + (tid & 127) * 4]) = pk_;  \
  } while (0)

__global__ __launch_bounds__(512) void lstm_rec(
    const float* __restrict__ cx, const float* __restrict__ w_hh,
    const unsigned short* __restrict__ gx_ws, unsigned int* __restrict__ h_tag,
    float* __restrict__ out) {
  const int bid = blockIdx.x;
  const int bg = bid & 7;    // batch-group (sync domain)
  const int nw = bid >> 3;   // col-group: h-cols [nw*64, +64)
  const int tid = threadIdx.x;
  const int lane = tid & 63;
  const int w = tid >> 6;
  __shared__ unsigned short As[4 * 536];   // h rows (bf16), stride 536
  __shared__ float Gt2[16 * 64];           // [tile n][cl*4+bq]
  __shared__ unsigned short GxL[2][1024];  // gx dbuf [bq][g][jl]

  // B-frags: 2 N-tiles (16 gate-cols each), full K=512 -> 128 VGPR
  bf16x8 breg[2][16];
#pragma unroll
  for (int q = 0; q < 2; ++q) {
    int n = w * 2 + q;
    int gcol = (n >> 2) * 512 + nw * 64 + (n & 3) * 16 + (lane & 15);
    const float* wrow = w_hh + (size_t)gcol * 512;
#pragma unroll
    for (int kk = 0; kk < 16; ++kk) {
      int k = kk * 32 + (lane >> 4) * 8;
      float4 f0 = *reinterpret_cast<const float4*>(wrow + k);
      float4 f1 = *reinterpret_cast<const float4*>(wrow + k + 4);
      uint4v v;
      v[0] = (unsigned)f2bf(f0.x) | ((unsigned)f2bf(f0.y) << 16);
      v[1] = (unsigned)f2bf(f0.z) | ((unsigned)f2bf(f0.w) << 16);
      v[2] = (unsigned)f2bf(f1.x) | ((unsigned)f2bf(f1.y) << 16);
      v[3] = (unsigned)f2bf(f1.z) | ((unsigned)f2bf(f1.w) << 16);
      breg[q][kk] = __builtin_bit_cast(bf16x8, v);
    }
  }
  // elementwise ownership (waves 0-3): bq=lane&3, cl=lane>>2, jl=w*16+cl
  const int bq = lane & 3;
  const int cl = lane >> 2;
  const int jl = (w & 3) * 16 + cl;
  const int col = nw * 64 + jl;
  const int bno = bg * 4 + bq;
  float c = 0.0f;
  if (w < 4) {
    c = cx[bno * 512 + col];
    asm volatile("" :: "v"(c));  // materialize pre-loop
  }

  unsigned int* slot0 = h_tag;
  unsigned int* slot1 = h_tag + 16384;
  const unsigned int* pollp0 = slot0 + bg * 2048 + tid * 4;
  const unsigned int* pollp1 = slot1 + bg * 2048 + tid * 4;
  unsigned int* pub0 = slot0 + bno * 512 + col;
  unsigned int* pub1 = slot1 + bno * 512 + col;
  const unsigned short* gx_base = gx_ws + ((size_t)bg * NCG + nw) * 1024;
  const size_t GXT = (size_t)NBG * NCG * 1024;  // elements per t
  const size_t BTH = (size_t)B_ * T_ * H_;

  uint4v hv;
  uint4v gxr;

  // ---- prologue: gx(0) (waves 0-1) + poll t=0 (tags seeded 0)
  if (w < 2)
    asm volatile("global_load_dwordx4 %0, %1, off"
                 : "=v"(gxr) : "v"(gx_base + (w * 64 + lane) * 8));
  POLLQ(pollp0);
  VMWAIT(0);
  SPIN4(pollp0, 0u);
  UNPACK_AS();
  if (w < 2)
    *reinterpret_cast<uint4v*>(&GxL[0][(w * 64 + lane) * 8]) =
        __builtin_bit_cast(uint4v, gxr);

  for (int t = 0; t < T_; ++t) {
    BARRIER_LGKM();  // A: As + GxL[t&1] ready
    const bool more = (t + 1 < T_);
    if (w < 2 && more)
      asm volatile("global_load_dwordx4 %0, %1, off"
                   : "=v"(gxr)
                   : "v"(gx_base + (size_t)(t + 1) * GXT + (w * 64 + lane) * 8));
    // ---- MFMA: 2 N-tiles, full K=512, 2 independent chains each
#pragma unroll
    for (int q = 0; q < 2; ++q) {
      f32x4 a0 = {}, a1 = {};
#pragma unroll
      for (int kk = 0; kk < 16; kk += 2) {
        bf16x8 af0 = *reinterpret_cast<const bf16x8*>(
            &As[(lane & 3) * 536 + kk * 32 + (lane >> 4) * 8]);
        bf16x8 af1 = *reinterpret_cast<const bf16x8*>(
            &As[(lane & 3) * 536 + (kk + 1) * 32 + (lane >> 4) * 8]);
        a0 = __builtin_amdgcn_mfma_f32_16x16x32_bf16(af0, breg[q][kk], a0, 0, 0, 0);
        a1 = __builtin_amdgcn_mfma_f32_16x16x32_bf16(af1, breg[q][kk + 1], a1, 0, 0, 0);
      }
      if (lane < 16) {
        f32x4 s4 = a0 + a1;  // acc[j] = batch j (A rows duplicated mod 4)
        *reinterpret_cast<f32x4*>(&Gt2[(w * 2 + q) * 64 + lane * 4]) = s4;
      }
    }
    BARRIER_LGKM();  // B: Gt2 complete
    const unsigned int* pollp = ((t + 1) & 1) ? pollp1 : pollp0;
    if (w >= 4) {
      if (more) {
        __builtin_amdgcn_s_sleep(5);  // ~320cy: align poll return w/ publish
        POLLQ(pollp);
      }
    } else {
      // ---- elementwise (waves 0-3): 256 outputs, 1 per thread
      const int gxb = t & 1;
      float s0, s1, s2, s3;
      {
        int n0 = 0 * 4 + (jl >> 4), n1 = 1 * 4 + (jl >> 4);
        int n2 = 2 * 4 + (jl >> 4), n3 = 3 * 4 + (jl >> 4);
        int idx = (jl & 15) * 4 + bq;
        s0 = Gt2[n0 * 64 + idx] + bf2f(GxL[gxb][bq * 256 + 0 * 64 + jl]);
        s1 = Gt2[n1 * 64 + idx] + bf2f(GxL[gxb][bq * 256 + 1 * 64 + jl]);
        s2 = Gt2[n2 * 64 + idx] + bf2f(GxL[gxb][bq * 256 + 2 * 64 + jl]);
        s3 = Gt2[n3 * 64 + idx] + bf2f(GxL[gxb][bq * 256 + 3 * 64 + jl]);
      }
      float ia = sigm(s0), fa = sigm(s1), ga = tanh_(s2), oa = sigm(s3);
      c = fa * c + ia * ga;
      float h = oa * tanh_(c);
      if (more) {  // publish first (critical path), then poll, then outs
        unsigned int word = (unsigned int)f2bf(h) | (((unsigned int)(t + 1)) << 16);
        unsigned int* q_ = ((t + 1) & 1) ? pub1 : pub0;
        asm volatile("global_store_dword %0, %1, off sc0 sc1" :: "v"(q_), "v"(word) : "memory");
        POLLQ(pollp);
      }
      size_t bo = (size_t)bno * (T_ * H_) + (size_t)t * H_ + col;
      asm volatile("global_store_dword %0, %1, off" :: "v"(out + bo), "v"(fa) : "memory");
      asm volatile("global_store_dword %0, %1, off"
                   :: "v"(out + BTH + bo), "v"(h) : "memory");
      asm volatile("global_store_dword %0, %1, off"
                   :: "v"(out + 2 * BTH + bo), "v"(ga) : "memory");
      if (!more) out[3 * BTH + (size_t)bno * H_ + col] = oa;
    }
    if (more) {
      // first wait: w<2 FIFO = [gxr][pub][poll][out*3] -> vmcnt(3);
      //             w==2,3  = [pub][poll][out*3]      -> vmcnt(3);
      //             w>=4    = [poll]                  -> vmcnt(0)
      if (w < 4) VMWAIT(3); else VMWAIT(0);
      SPIN4(pollp, t + 1);
      UNPACK_AS();
      if (w < 2)
        *reinterpret_cast<uint4v*>(&GxL[(t + 1) & 1][(w * 64 + lane) * 8]) =
            __builtin_bit_cast(uint4v, gxr);
    }
  }
}

extern "C" void kernel_launch(void* const* d_in, const int* in_sizes, int n_in,
                              void* d_out, int out_size, void* d_ws, size_t ws_size,
                              hipStream_t stream) {
  const float* x    = (const float*)d_in[0];
  const float* hx   = (const float*)d_in[1];
  const float* cx   = (const float*)d_in[2];
  const float* w_ih = (const float*)d_in[3];
  const float* w_hh = (const float*)d_in[4];
  const float* b_ih = (const float*)d_in[5];
  const float* b_hh = (const float*)d_in[6];
  float* out = (float*)d_out;
  char* ws = (char*)d_ws;
  const size_t OFF_XBF  = 0;                    // 67,108,864
  const size_t OFF_WBF  = 67108864;             //  2,097,152
  const size_t OFF_GX   = 69206016;             // 268,435,456
  const size_t OFF_HTAG = 337641472;            //    131,072
  const size_t NEEDED   = 337772544;
  if (ws_size < NEEDED) return;

  unsigned short* x_bf  = (unsigned short*)(ws + OFF_XBF);
  unsigned short* w_bf  = (unsigned short*)(ws + OFF_WBF);
  unsigned short* gx_ws = (unsigned short*)(ws + OFF_GX);
  unsigned int*   h_tag = (unsigned int*)(ws + OFF_HTAG);

  prep_kernel<<<16912, 256, 0, stream>>>(x, w_ih, hx, x_bf, w_bf, h_tag);
  gemm_gx<<<8192, 256, 0, stream>>>(x_bf, w_bf, b_ih, b_hh, gx_ws);
  lstm_rec<<<64, 512, 0, stream>>>(cx, w_hh, gx_ws, h_tag, out);
}

// Round 12
// 5718.575 us; speedup vs baseline: 1.2247x; 1.0737x over previous
//
#include <hip/hip_runtime.h>
#include <stdint.h>

// LSTM forward, B=32 T=2048 D=512 H=512 G=2048.
// Round 12 = round 6 structure (best: 5.12ms) with two targeted fixes:
//  (1) DEFERRED OUT-STORES: elem waves keep {fa,h,ga} in registers and store
//      them at the TOP of the next iteration (after barrier A). vmcnt is
//      FIFO, so r6's retry VMWAIT(0) was draining out-store HBM acks
//      (~600-1000cy) on the critical path; now retries wait only [pub][poll].
//  (2) Pure sc0sc1 polls (r8 evidence: sc0 fast tries return stale data
//      until the MALL RTT anyway - pure waste). No entry fence (r5-proven).
// Protocol: tagged dwords (lo16 bf16 h | hi16 step), double-buffered slots,
// tag+payload share a dword => no fences. 128 WGs = 16 col x 8 batch-groups.

#define B_ 32
#define T_ 2048
#define D_ 512
#define H_ 512
#define G_ 2048
#define NCG 16
#define NBG 8

typedef __attribute__((ext_vector_type(4))) float f32x4;
typedef __attribute__((ext_vector_type(8))) short bf16x8;
typedef __attribute__((ext_vector_type(4))) unsigned int uint4v;
typedef __attribute__((ext_vector_type(2))) unsigned int uint2v;

__device__ __forceinline__ unsigned short f2bf(float f) {
  union { float f; unsigned int u; } v; v.f = f;
  unsigned int r = (v.u + 0x7FFFu + ((v.u >> 16) & 1u)) >> 16;
  return (unsigned short)r;
}
__device__ __forceinline__ float bf2f(unsigned short s) {
  union { unsigned int u; float f; } v; v.u = ((unsigned int)s) << 16;
  return v.f;
}
__device__ __forceinline__ float sigm(float x) { return 1.0f / (1.0f + __expf(-x)); }
__device__ __forceinline__ float tanh_(float x) { return 1.0f - 2.0f / (__expf(2.0f * x) + 1.0f); }

__device__ __forceinline__ void store_x4_coherent(unsigned int* p, uint4v v) {
  asm volatile("global_store_dwordx4 %0, %1, off sc0 sc1" :: "v"(p), "v"(v) : "memory");
}

#define BARRIER_LGKM()                                          \
  do {                                                          \
    asm volatile("s_waitcnt lgkmcnt(0)" ::: "memory");          \
    __builtin_amdgcn_sched_barrier(0);                          \
    __builtin_amdgcn_s_barrier();                               \
    __builtin_amdgcn_sched_barrier(0);                          \
  } while (0)

#define VMWAIT(N)                                               \
  do { asm volatile("s_waitcnt vmcnt(" #N ")" ::: "memory");    \
       __builtin_amdgcn_sched_barrier(0); } while (0)

// ---------------- Phase 1: convert inputs + seed/clear h_tag ----------------
__global__ __launch_bounds__(256) void prep_kernel(
    const float* __restrict__ x, const float* __restrict__ w_ih,
    const float* __restrict__ hx,
    unsigned short* __restrict__ x_bf, unsigned short* __restrict__ w_bf,
    unsigned int* __restrict__ h_tag) {
  const int NX8 = (B_ * T_ * D_) / 8;   // 4,194,304
  const int NWT8 = (G_ * D_) / 8;       // 131,072
  int i = blockIdx.x * 256 + threadIdx.x;
  if (i < NX8) {
    float4 a = reinterpret_cast<const float4*>(x)[i * 2];
    float4 b = reinterpret_cast<const float4*>(x)[i * 2 + 1];
    uint4v v;
    v[0] = (unsigned)f2bf(a.x) | ((unsigned)f2bf(a.y) << 16);
    v[1] = (unsigned)f2bf(a.z) | ((unsigned)f2bf(a.w) << 16);
    v[2] = (unsigned)f2bf(b.x) | ((unsigned)f2bf(b.y) << 16);
    v[3] = (unsigned)f2bf(b.z) | ((unsigned)f2bf(b.w) << 16);
    reinterpret_cast<uint4v*>(x_bf)[i] = v;
  } else if (i < NX8 + NWT8) {
    int j = i - NX8;
    float4 a = reinterpret_cast<const float4*>(w_ih)[j * 2];
    float4 b = reinterpret_cast<const float4*>(w_ih)[j * 2 + 1];
    uint4v v;
    v[0] = (unsigned)f2bf(a.x) | ((unsigned)f2bf(a.y) << 16);
    v[1] = (unsigned)f2bf(a.z) | ((unsigned)f2bf(a.w) << 16);
    v[2] = (unsigned)f2bf(b.x) | ((unsigned)f2bf(b.y) << 16);
    v[3] = (unsigned)f2bf(b.z) | ((unsigned)f2bf(b.w) << 16);
    reinterpret_cast<uint4v*>(w_bf)[j] = v;
  } else if (i < NX8 + NWT8 + 2048) {
    int j = i - NX8 - NWT8;  // seed slot 0 from hx, tag 0
    float4 a = reinterpret_cast<const float4*>(hx)[j * 2];
    float4 b = reinterpret_cast<const float4*>(hx)[j * 2 + 1];
    uint4v v0, v1;
    v0[0] = f2bf(a.x); v0[1] = f2bf(a.y); v0[2] = f2bf(a.z); v0[3] = f2bf(a.w);
    v1[0] = f2bf(b.x); v1[1] = f2bf(b.y); v1[2] = f2bf(b.z); v1[3] = f2bf(b.w);
    unsigned int* p = h_tag + j * 8;
    store_x4_coherent(p, v0);
    store_x4_coherent(p + 4, v1);
  } else {
    int j = i - NX8 - NWT8 - 2048;  // clear slot 1
    unsigned int* p = h_tag + 16384 + j * 8;
    uint4v z = {0u, 0u, 0u, 0u};
    store_x4_coherent(p, z);
    store_x4_coherent(p + 4, z);
  }
}

// ---------------- Phase 2: gx GEMM (r6 layout, NCG=16) ----------------
__global__ __launch_bounds__(256, 2) void gemm_gx(
    const unsigned short* __restrict__ x_bf, const unsigned short* __restrict__ w_bf,
    const float* __restrict__ b_ih, const float* __restrict__ b_hh,
    unsigned short* __restrict__ gx_ws) {
  __shared__ unsigned short As[128 * 40];
  __shared__ unsigned short Bs[128 * 40];
  __shared__ unsigned short Eg[128 * 136];
  const int bid = blockIdx.x;
  const int cb = bid & 15, rb = bid >> 4;
  const int r0 = rb * 128, c0 = cb * 128;
  const int tid = threadIdx.x;
  const int lane = tid & 63;
  const int w = tid >> 6;
  const int qr = (w >> 1) * 64, qc = (w & 1) * 64;
  f32x4 acc[4][4] = {};

  for (int kt = 0; kt < 16; ++kt) {
    const int k0 = kt * 32;
    uint4v av[2], bv[2];
#pragma unroll
    for (int c = 0; c < 2; ++c) {
      int flat = c * 256 + tid;
      int row = flat >> 2, q = flat & 3;
      av[c] = *reinterpret_cast<const uint4v*>(x_bf + (size_t)(r0 + row) * 512 + k0 + q * 8);
      bv[c] = *reinterpret_cast<const uint4v*>(w_bf + (size_t)(c0 + row) * 512 + k0 + q * 8);
    }
    __syncthreads();
#pragma unroll
    for (int c = 0; c < 2; ++c) {
      int flat = c * 256 + tid;
      int row = flat >> 2, q = flat & 3;
      *reinterpret_cast<uint4v*>(&As[row * 40 + q * 8]) = av[c];
      *reinterpret_cast<uint4v*>(&Bs[row * 40 + q * 8]) = bv[c];
    }
    __syncthreads();
    bf16x8 af[4], bfr[4];
#pragma unroll
    for (int mt = 0; mt < 4; ++mt)
      af[mt] = *reinterpret_cast<const bf16x8*>(&As[(qr + mt * 16 + (lane & 15)) * 40 + (lane >> 4) * 8]);
#pragma unroll
    for (int nt = 0; nt < 4; ++nt)
      bfr[nt] = *reinterpret_cast<const bf16x8*>(&Bs[(qc + nt * 16 + (lane & 15)) * 40 + (lane >> 4) * 8]);
#pragma unroll
    for (int mt = 0; mt < 4; ++mt)
#pragma unroll
      for (int nt = 0; nt < 4; ++nt)
        acc[mt][nt] = __builtin_amdgcn_mfma_f32_16x16x32_bf16(af[mt], bfr[nt], acc[mt][nt], 0, 0, 0);
  }
  __syncthreads();
#pragma unroll
  for (int nt = 0; nt < 4; ++nt) {
    int cg = c0 + qc + nt * 16 + (lane & 15);
    float bias = b_ih[cg] + b_hh[cg];
#pragma unroll
    for (int mt = 0; mt < 4; ++mt)
#pragma unroll
      for (int j = 0; j < 4; ++j) {
        int tr = qr + mt * 16 + (lane >> 4) * 4 + j;
        int cl = qc + nt * 16 + (lane & 15);
        Eg[tr * 136 + cl] = f2bf(acc[mt][nt][j] + bias);
      }
  }
  __syncthreads();
  const int b = r0 >> 11;          // batch, constant per tile
  const int g = c0 >> 9;           // gate, constant per tile
  const int t0 = r0 & 2047;
  const int nw0 = (c0 & 511) >> 5; // 4 col-groups per tile
  const int bg = b >> 2, bq = b & 3;
  for (int c = tid; c < 512; c += 256) {
    int tr = c >> 2, nwi = c & 3;
    size_t dst = (((size_t)(t0 + tr) * NBG + bg) * NCG + (nw0 + nwi)) * 512 + bq * 128 + g * 32;
    const unsigned short* src = &Eg[tr * 136 + nwi * 32];
#pragma unroll
    for (int q = 0; q < 4; ++q)
      *reinterpret_cast<uint4v*>(gx_ws + dst + q * 8) =
          *reinterpret_cast<const uint4v*>(src + q * 8);
  }
}

// ---------------- Phase 3: recurrence ----------------
#define POLLQ(PP) \
  asm volatile("global_load_dwordx4 %0, %1, off sc0 sc1" : "=v"(hv) : "v"(PP))

__global__ __launch_bounds__(512) void lstm_rec(
    const float* __restrict__ cx, const float* __restrict__ w_hh,
    const unsigned short* __restrict__ gx_ws, unsigned int* __restrict__ h_tag,
    float* __restrict__ out) {
  const int bid = blockIdx.x;
  const int bg = bid & 7;    // batch-group (sync domain)
  const int nw = bid >> 3;   // col-group: h-cols [nw*32, +32)
  const int tid = threadIdx.x;
  const int lane = tid & 63;
  const int w = tid >> 6;
  const int gi = w >> 1;
  const int half = w & 1;
  __shared__ unsigned short As[4 * 536];   // h rows (bf16), stride 536
  __shared__ float Gt2[8 * 64];            // [tile n][cl*4+bq]
  __shared__ unsigned short GxL[2][512];   // gx dbuf [bq][g][jl]

  // B-frags: one N-tile (16 gate-cols), full K=512 -> 16 frags = 64 VGPR
  bf16x8 breg[16];
  {
    int gcol = gi * 512 + nw * 32 + half * 16 + (lane & 15);
    const float* wrow = w_hh + (size_t)gcol * 512;
#pragma unroll
    for (int kk = 0; kk < 16; ++kk) {
      int k = kk * 32 + (lane >> 4) * 8;
      float4 f0 = *reinterpret_cast<const float4*>(wrow + k);
      float4 f1 = *reinterpret_cast<const float4*>(wrow + k + 4);
      uint4v v;
      v[0] = (unsigned)f2bf(f0.x) | ((unsigned)f2bf(f0.y) << 16);
      v[1] = (unsigned)f2bf(f0.z) | ((unsigned)f2bf(f0.w) << 16);
      v[2] = (unsigned)f2bf(f1.x) | ((unsigned)f2bf(f1.y) << 16);
      v[3] = (unsigned)f2bf(f1.z) | ((unsigned)f2bf(f1.w) << 16);
      breg[kk] = __builtin_bit_cast(bf16x8, v);
    }
  }
  // elementwise ownership (waves 0,1): bq=lane&3, cl=lane>>2, jl=w*16+cl
  const int bq = lane & 3;
  const int cl = lane >> 2;
  const int jl = (w & 1) * 16 + cl;
  const int col = nw * 32 + jl;
  const int bno = bg * 4 + bq;
  float c = 0.0f;
  if (w < 2) {
    c = cx[bno * 512 + col];
    asm volatile("" :: "v"(c));  // materialize pre-loop
  }

  unsigned int* slot0 = h_tag;
  unsigned int* slot1 = h_tag + 16384;
  const unsigned int* pollp0 = slot0 + bg * 2048 + tid * 4;
  const unsigned int* pollp1 = slot1 + bg * 2048 + tid * 4;
  unsigned int* pub0 = slot0 + bno * 512 + col;
  unsigned int* pub1 = slot1 + bno * 512 + col;
  const unsigned short* gx_base = gx_ws + ((size_t)bg * NCG + nw) * 512;
  const size_t GXT = (size_t)NBG * NCG * 512;  // elements per t
  const size_t BTH = (size_t)B_ * T_ * H_;

  uint4v hv;
  uint4v gxr;
  float pfa = 0.0f, ph = 0.0f, pga = 0.0f;  // deferred out values (step t-1)

  // ---- prologue: gx(0) + poll t=0 (tags seeded 0)
  if (w == 0)
    asm volatile("global_load_dwordx4 %0, %1, off"
                 : "=v"(gxr) : "v"(gx_base + lane * 8));
  {
    POLLQ(pollp0);
    VMWAIT(0);
    unsigned bad = (hv[0] >> 16) | (hv[1] >> 16) | (hv[2] >> 16) | (hv[3] >> 16);
    int guard = 0;
    while (bad) {
      POLLQ(pollp0);
      VMWAIT(0);
      bad = (hv[0] >> 16) | (hv[1] >> 16) | (hv[2] >> 16) | (hv[3] >> 16);
      if (++guard > (1 << 20)) break;
    }
    uint2v pk;
    pk[0] = (hv[0] & 0xffffu) | (hv[1] << 16);
    pk[1] = (hv[2] & 0xffffu) | (hv[3] << 16);
    *reinterpret_cast<uint2v*>(&As[(tid >> 7) * 536 + (tid & 127) * 4]) = pk;
  }
  if (w == 0)
    *reinterpret_cast<uint4v*>(&GxL[0][lane * 8]) = __builtin_bit_cast(uint4v, gxr);

  for (int t = 0; t < T_; ++t) {
    BARRIER_LGKM();  // A: As + GxL[t&1] ready
    const bool more = (t + 1 < T_);
    // ---- deferred out-stores for step t-1 (issued early; age across MFMA)
    if (w < 2 && t) {
      size_t bo = (size_t)bno * (T_ * H_) + (size_t)(t - 1) * H_ + col;
      asm volatile("global_store_dword %0, %1, off" :: "v"(out + bo), "v"(pfa) : "memory");
      asm volatile("global_store_dword %0, %1, off"
                   :: "v"(out + BTH + bo), "v"(ph) : "memory");
      asm volatile("global_store_dword %0, %1, off"
                   :: "v"(out + 2 * BTH + bo), "v"(pga) : "memory");
    }
    if (w == 0 && more)
      asm volatile("global_load_dwordx4 %0, %1, off"
                   : "=v"(gxr) : "v"(gx_base + (size_t)(t + 1) * GXT + lane * 8));
    // ---- MFMA: full K=512, one N-tile per wave; 2 independent chains
    f32x4 a0 = {}, a1 = {};
#pragma unroll
    for (int kk = 0; kk < 16; kk += 2) {
      bf16x8 af0 = *reinterpret_cast<const bf16x8*>(
          &As[(lane & 3) * 536 + kk * 32 + (lane >> 4) * 8]);
      bf16x8 af1 = *reinterpret_cast<const bf16x8*>(
          &As[(lane & 3) * 536 + (kk + 1) * 32 + (lane >> 4) * 8]);
      a0 = __builtin_amdgcn_mfma_f32_16x16x32_bf16(af0, breg[kk], a0, 0, 0, 0);
      a1 = __builtin_amdgcn_mfma_f32_16x16x32_bf16(af1, breg[kk + 1], a1, 0, 0, 0);
    }
    if (lane < 16) {
      f32x4 s4 = a0 + a1;  // C rows 0-3 = batches 0-3, col = lane
      *reinterpret_cast<f32x4*>(&Gt2[w * 64 + lane * 4]) = s4;
    }
    BARRIER_LGKM();  // B: Gt2 complete
    const unsigned int* pollp = ((t + 1) & 1) ? pollp1 : pollp0;
    if (w >= 2) {
      if (more) POLLQ(pollp);
    } else {
      // ---- elementwise (waves 0,1): 128 outputs, 4 LDS reads each
      const int gxb = t & 1;
      float s0 = Gt2[(0 * 2 + w) * 64 + lane] + bf2f(GxL[gxb][bq * 128 + 0 * 32 + jl]);
      float s1 = Gt2[(1 * 2 + w) * 64 + lane] + bf2f(GxL[gxb][bq * 128 + 1 * 32 + jl]);
      float s2 = Gt2[(2 * 2 + w) * 64 + lane] + bf2f(GxL[gxb][bq * 128 + 2 * 32 + jl]);
      float s3 = Gt2[(3 * 2 + w) * 64 + lane] + bf2f(GxL[gxb][bq * 128 + 3 * 32 + jl]);
      float ia = sigm(s0), fa = sigm(s1), ga = tanh_(s2), oa = sigm(s3);
      c = fa * c + ia * ga;
      float h = oa * tanh_(c);
      if (more) {
        // publish first (critical path), then poll; out-stores DEFERRED
        unsigned int word = (unsigned int)f2bf(h) | (((unsigned int)(t + 1)) << 16);
        unsigned int* q_ = ((t + 1) & 1) ? pub1 : pub0;
        asm volatile("global_store_dword %0, %1, off sc0 sc1" :: "v"(q_), "v"(word) : "memory");
        POLLQ(pollp);
        pfa = fa; ph = h; pga = ga;  // stored at top of next iteration
      } else {
        // last step: store everything directly (no next iteration)
        size_t bo = (size_t)bno * (T_ * H_) + (size_t)t * H_ + col;
        asm volatile("global_store_dword %0, %1, off" :: "v"(out + bo), "v"(fa) : "memory");
        asm volatile("global_store_dword %0, %1, off"
                     :: "v"(out + BTH + bo), "v"(h) : "memory");
        asm volatile("global_store_dword %0, %1, off"
                     :: "v"(out + 2 * BTH + bo), "v"(ga) : "memory");
        out[3 * BTH + (size_t)bno * H_ + col] = oa;
      }
    }
    if (more) {
      // all older VMEM (deferred outs, gxr) aged across MFMA+2 barriers ->
      // VMWAIT(0) effectively waits only [pub][poll] (first) / [poll] (retry)
      VMWAIT(0);
      const unsigned want = (unsigned)(t + 1);
      unsigned bad = ((hv[0] >> 16) ^ want) | ((hv[1] >> 16) ^ want) |
                     ((hv[2] >> 16) ^ want) | ((hv[3] >> 16) ^ want);
      int guard = 0;
      while (bad) {
        POLLQ(pollp);
        VMWAIT(0);
        bad = ((hv[0] >> 16) ^ want) | ((hv[1] >> 16) ^ want) |
              ((hv[2] >> 16) ^ want) | ((hv[3] >> 16) ^ want);
        if (++guard > (1 << 20)) break;
      }
      uint2v pk;
      pk[0] = (hv[0] & 0xffffu) | (hv[1] << 16);
      pk[1] = (hv[2] & 0xffffu) | (hv[3] << 16);
      *reinterpret_cast<uint2v*>(&As[(tid >> 7) * 536 + (tid & 127) * 4]) = pk;
      if (w == 0)
        *reinterpret_cast<uint4v*>(&GxL[(t + 1) & 1][lane * 8]) = __builtin_bit_cast(uint4v, gxr);
    }
  }
}

extern "C" void kernel_launch(void* const* d_in, const int* in_sizes, int n_in,
                              void* d_out, int out_size, void* d_ws, size_t ws_size,
                              hipStream_t stream) {
  const float* x    = (const float*)d_in[0];
  const float* hx   = (const float*)d_in[1];
  const float* cx   = (const float*)d_in[2];
  const float* w_ih = (const float*)d_in[3];
  const float* w_hh = (const float*)d_in[4];
  const float* b_ih = (const float*)d_in[5];
  const float* b_hh = (const float*)d_in[6];
  float* out = (float*)d_out;
  char* ws = (char*)d_ws;
  const size_t OFF_XBF  = 0;                    // 67,108,864
  const size_t OFF_WBF  = 67108864;             //  2,097,152
  const size_t OFF_GX   = 69206016;             // 268,435,456
  const size_t OFF_HTAG = 337641472;            //    131,072
  const size_t NEEDED   = 337772544;
  if (ws_size < NEEDED) return;

  unsigned short* x_bf  = (unsigned short*)(ws + OFF_XBF);
  unsigned short* w_bf  = (unsigned short*)(ws + OFF_WBF);
  unsigned short* gx_ws = (unsigned short*)(ws + OFF_GX);
  unsigned int*   h_tag = (unsigned int*)(ws + OFF_HTAG);

  prep_kernel<<<16912, 256, 0, stream>>>(x, w_ih, hx, x_bf, w_bf, h_tag);
  gemm_gx<<<8192, 256, 0, stream>>>(x_bf, w_bf, b_ih, b_hh, gx_ws);
  lstm_rec<<<128, 512, 0, stream>>>(cx, w_hh, gx_ws, h_tag, out);
}

// Round 13
// 4981.940 us; speedup vs baseline: 1.4058x; 1.1479x over previous
//
#include <hip/hip_runtime.h>
#include <stdint.h>

// LSTM forward, B=32 T=2048 D=512 H=512 G=2048.
// Round 13 = r12 + XCD-VERIFIED local exchange:
//  - Each WG reads its real XCD via s_getreg(HW_REG_XCC_ID) and claims a
//    (batch-group=domain, col-group) slot from an atomic claim table grouped
//    by XCD: domain k's 16 WGs all land on XCD k when the scheduler balances
//    (16 WGs/XCD for a uniform 128-WG launch). No static bid->XCD assumption.
//  - Dual publish: plain store (updates the SHARED local L2 line in place ->
//    co-located consumers' sc0 polls read a LIVE line) then sc0sc1 (MALL,
//    correctness fallback for any misplaced WG).
//  - Polls: sc0 fast (live local L2); retries 1-3 fast then sc0sc1.
//  - Own-column LDS self-injection (owners ds_write h into As) so polls can
//    precede publishes in the wave FIFO; check = counted VMWAIT(2) -> never
//    waits on pub/out store acks.
// Protocol: tagged dwords (lo16 bf16 h | hi16 step), double-buffered slots,
// tag+payload share a dword => no fences. Deterministic output regardless of
// which WG claims which slot.

#define B_ 32
#define T_ 2048
#define D_ 512
#define H_ 512
#define G_ 2048
#define NCG 16
#define NBG 8

typedef __attribute__((ext_vector_type(4))) float f32x4;
typedef __attribute__((ext_vector_type(8))) short bf16x8;
typedef __attribute__((ext_vector_type(4))) unsigned int uint4v;
typedef __attribute__((ext_vector_type(2))) unsigned int uint2v;

__device__ __forceinline__ unsigned short f2bf(float f) {
  union { float f; unsigned int u; } v; v.f = f;
  unsigned int r = (v.u + 0x7FFFu + ((v.u >> 16) & 1u)) >> 16;
  return (unsigned short)r;
}
__device__ __forceinline__ float bf2f(unsigned short s) {
  union { unsigned int u; float f; } v; v.u = ((unsigned int)s) << 16;
  return v.f;
}
__device__ __forceinline__ float sigm(float x) { return 1.0f / (1.0f + __expf(-x)); }
__device__ __forceinline__ float tanh_(float x) { return 1.0f - 2.0f / (__expf(2.0f * x) + 1.0f); }

__device__ __forceinline__ void store_x4_coherent(unsigned int* p, uint4v v) {
  asm volatile("global_store_dwordx4 %0, %1, off sc0 sc1" :: "v"(p), "v"(v) : "memory");
}

#define BARRIER_LGKM()                                          \
  do {                                                          \
    asm volatile("s_waitcnt lgkmcnt(0)" ::: "memory");          \
    __builtin_amdgcn_sched_barrier(0);                          \
    __builtin_amdgcn_s_barrier();                               \
    __builtin_amdgcn_sched_barrier(0);                          \
  } while (0)

#define VMWAIT(N)                                               \
  do { asm volatile("s_waitcnt vmcnt(" #N ")" ::: "memory");    \
       __builtin_amdgcn_sched_barrier(0); } while (0)

// ---------------- Phase 1: convert inputs + seed/clear h_tag + ctrl --------
__global__ __launch_bounds__(256) void prep_kernel(
    const float* __restrict__ x, const float* __restrict__ w_ih,
    const float* __restrict__ hx,
    unsigned short* __restrict__ x_bf, unsigned short* __restrict__ w_bf,
    unsigned int* __restrict__ h_tag, unsigned int* __restrict__ ctrl) {
  const int NX8 = (B_ * T_ * D_) / 8;   // 4,194,304
  const int NWT8 = (G_ * D_) / 8;       // 131,072
  const int A = NX8 + NWT8;
  int i = blockIdx.x * 256 + threadIdx.x;
  if (i < NX8) {
    float4 a = reinterpret_cast<const float4*>(x)[i * 2];
    float4 b = reinterpret_cast<const float4*>(x)[i * 2 + 1];
    uint4v v;
    v[0] = (unsigned)f2bf(a.x) | ((unsigned)f2bf(a.y) << 16);
    v[1] = (unsigned)f2bf(a.z) | ((unsigned)f2bf(a.w) << 16);
    v[2] = (unsigned)f2bf(b.x) | ((unsigned)f2bf(b.y) << 16);
    v[3] = (unsigned)f2bf(b.z) | ((unsigned)f2bf(b.w) << 16);
    reinterpret_cast<uint4v*>(x_bf)[i] = v;
  } else if (i < A) {
    int j = i - NX8;
    float4 a = reinterpret_cast<const float4*>(w_ih)[j * 2];
    float4 b = reinterpret_cast<const float4*>(w_ih)[j * 2 + 1];
    uint4v v;
    v[0] = (unsigned)f2bf(a.x) | ((unsigned)f2bf(a.y) << 16);
    v[1] = (unsigned)f2bf(a.z) | ((unsigned)f2bf(a.w) << 16);
    v[2] = (unsigned)f2bf(b.x) | ((unsigned)f2bf(b.y) << 16);
    v[3] = (unsigned)f2bf(b.z) | ((unsigned)f2bf(b.w) << 16);
    reinterpret_cast<uint4v*>(w_bf)[j] = v;
  } else if (i < A + 2048) {
    int j = i - A;  // seed slot 0 from hx, tag 0
    float4 a = reinterpret_cast<const float4*>(hx)[j * 2];
    float4 b = reinterpret_cast<const float4*>(hx)[j * 2 + 1];
    uint4v v0, v1;
    v0[0] = f2bf(a.x); v0[1] = f2bf(a.y); v0[2] = f2bf(a.z); v0[3] = f2bf(a.w);
    v1[0] = f2bf(b.x); v1[1] = f2bf(b.y); v1[2] = f2bf(b.z); v1[3] = f2bf(b.w);
    unsigned int* p = h_tag + j * 8;
    store_x4_coherent(p, v0);
    store_x4_coherent(p + 4, v1);
  } else if (i < A + 4096) {
    int j = i - A - 2048;  // clear slot 1
    unsigned int* p = h_tag + 16384 + j * 8;
    uint4v z = {0u, 0u, 0u, 0u};
    store_x4_coherent(p, z);
    store_x4_coherent(p + 4, z);
  } else {
    int j = i - A - 4096;  // clear ctrl (counters + claim table), 256 dwords
    unsigned int* p = ctrl + j;
    unsigned int z = 0u;
    asm volatile("global_store_dword %0, %1, off sc0 sc1" :: "v"(p), "v"(z) : "memory");
  }
}

// ---------------- Phase 2: gx GEMM (r12 layout, NCG=16) ----------------
__global__ __launch_bounds__(256, 2) void gemm_gx(
    const unsigned short* __restrict__ x_bf, const unsigned short* __restrict__ w_bf,
    const float* __restrict__ b_ih, const float* __restrict__ b_hh,
    unsigned short* __restrict__ gx_ws) {
  __shared__ unsigned short As[128 * 40];
  __shared__ unsigned short Bs[128 * 40];
  __shared__ unsigned short Eg[128 * 136];
  const int bid = blockIdx.x;
  const int cb = bid & 15, rb = bid >> 4;
  const int r0 = rb * 128, c0 = cb * 128;
  const int tid = threadIdx.x;
  const int lane = tid & 63;
  const int w = tid >> 6;
  const int qr = (w >> 1) * 64, qc = (w & 1) * 64;
  f32x4 acc[4][4] = {};

  for (int kt = 0; kt < 16; ++kt) {
    const int k0 = kt * 32;
    uint4v av[2], bv[2];
#pragma unroll
    for (int c = 0; c < 2; ++c) {
      int flat = c * 256 + tid;
      int row = flat >> 2, q = flat & 3;
      av[c] = *reinterpret_cast<const uint4v*>(x_bf + (size_t)(r0 + row) * 512 + k0 + q * 8);
      bv[c] = *reinterpret_cast<const uint4v*>(w_bf + (size_t)(c0 + row) * 512 + k0 + q * 8);
    }
    __syncthreads();
#pragma unroll
    for (int c = 0; c < 2; ++c) {
      int flat = c * 256 + tid;
      int row = flat >> 2, q = flat & 3;
      *reinterpret_cast<uint4v*>(&As[row * 40 + q * 8]) = av[c];
      *reinterpret_cast<uint4v*>(&Bs[row * 40 + q * 8]) = bv[c];
    }
    __syncthreads();
    bf16x8 af[4], bfr[4];
#pragma unroll
    for (int mt = 0; mt < 4; ++mt)
      af[mt] = *reinterpret_cast<const bf16x8*>(&As[(qr + mt * 16 + (lane & 15)) * 40 + (lane >> 4) * 8]);
#pragma unroll
    for (int nt = 0; nt < 4; ++nt)
      bfr[nt] = *reinterpret_cast<const bf16x8*>(&Bs[(qc + nt * 16 + (lane & 15)) * 40 + (lane >> 4) * 8]);
#pragma unroll
    for (int mt = 0; mt < 4; ++mt)
#pragma unroll
      for (int nt = 0; nt < 4; ++nt)
        acc[mt][nt] = __builtin_amdgcn_mfma_f32_16x16x32_bf16(af[mt], bfr[nt], acc[mt][nt], 0, 0, 0);
  }
  __syncthreads();
#pragma unroll
  for (int nt = 0; nt < 4; ++nt) {
    int cg = c0 + qc + nt * 16 + (lane & 15);
    float bias = b_ih[cg] + b_hh[cg];
#pragma unroll
    for (int mt = 0; mt < 4; ++mt)
#pragma unroll
      for (int j = 0; j < 4; ++j) {
        int tr = qr + mt * 16 + (lane >> 4) * 4 + j;
        int cl = qc + nt * 16 + (lane & 15);
        Eg[tr * 136 + cl] = f2bf(acc[mt][nt][j] + bias);
      }
  }
  __syncthreads();
  const int b = r0 >> 11;
  const int g = c0 >> 9;
  const int t0 = r0 & 2047;
  const int nw0 = (c0 & 511) >> 5;
  const int bg = b >> 2, bq = b & 3;
  for (int c = tid; c < 512; c += 256) {
    int tr = c >> 2, nwi = c & 3;
    size_t dst = (((size_t)(t0 + tr) * NBG + bg) * NCG + (nw0 + nwi)) * 512 + bq * 128 + g * 32;
    const unsigned short* src = &Eg[tr * 136 + nwi * 32];
#pragma unroll
    for (int q = 0; q < 4; ++q)
      *reinterpret_cast<uint4v*>(gx_ws + dst + q * 8) =
          *reinterpret_cast<const uint4v*>(src + q * 8);
  }
}

// ---------------- Phase 3: recurrence ----------------
#define POLLF(PP) \
  asm volatile("global_load_dwordx4 %0, %1, off sc0" : "=v"(hv) : "v"(PP))
#define POLLS(PP) \
  asm volatile("global_load_dwordx4 %0, %1, off sc0 sc1" : "=v"(hv) : "v"(PP))

__global__ __launch_bounds__(512) void lstm_rec(
    const float* __restrict__ cx, const float* __restrict__ w_hh,
    const unsigned short* __restrict__ gx_ws, unsigned int* __restrict__ h_tag,
    unsigned int* __restrict__ ctrl, float* __restrict__ out) {
  const int tid = threadIdx.x;
  const int lane = tid & 63;
  const int w = tid >> 6;
  __shared__ unsigned short As[4 * 536];   // h rows (bf16), stride 536
  __shared__ float Gt2[8 * 64];            // [tile n][cl*4+bq]
  __shared__ unsigned short GxL[2][512];   // gx dbuf [bq][g][jl]
  __shared__ int sdr[2];

  // ---- dynamic XCD-grouped slot claim: domain = this WG's real XCD ----
  if (tid == 0) {
    int xcd;
    asm volatile("s_getreg_b32 %0, hwreg(HW_REG_XCC_ID)" : "=s"(xcd));
    xcd &= 7;
    unsigned int* cnt = ctrl;        // [8] per-XCD counters
    unsigned int* clm = ctrl + 8;    // [128] claim flags
    int slot = -1;
    unsigned role = atomicAdd(&cnt[xcd], 1u);
    if (role < 16u) {
      if (atomicCAS(&clm[xcd * 16 + role], 0u, 1u) == 0u)
        slot = xcd * 16 + (int)role;
    }
    while (slot < 0) {               // overflow: steal any free slot
      for (int s = 0; s < 128 && slot < 0; ++s)
        if (atomicCAS(&clm[s], 0u, 1u) == 0u) slot = s;
    }
    sdr[0] = slot >> 4;   // bg (domain == XCD when balanced)
    sdr[1] = slot & 15;   // nw (col-group)
  }
  __syncthreads();
  const int bg = sdr[0];
  const int nw = sdr[1];
  const int gi = w >> 1;
  const int half = w & 1;
  const bool ownq = (((tid & 127) >> 3) == nw);  // poll dwords are own cols

  // B-frags: one N-tile (16 gate-cols), full K=512 -> 16 frags = 64 VGPR
  bf16x8 breg[16];
  {
    int gcol = gi * 512 + nw * 32 + half * 16 + (lane & 15);
    const float* wrow = w_hh + (size_t)gcol * 512;
#pragma unroll
    for (int kk = 0; kk < 16; ++kk) {
      int k = kk * 32 + (lane >> 4) * 8;
      float4 f0 = *reinterpret_cast<const float4*>(wrow + k);
      float4 f1 = *reinterpret_cast<const float4*>(wrow + k + 4);
      uint4v v;
      v[0] = (unsigned)f2bf(f0.x) | ((unsigned)f2bf(f0.y) << 16);
      v[1] = (unsigned)f2bf(f0.z) | ((unsigned)f2bf(f0.w) << 16);
      v[2] = (unsigned)f2bf(f1.x) | ((unsigned)f2bf(f1.y) << 16);
      v[3] = (unsigned)f2bf(f1.z) | ((unsigned)f2bf(f1.w) << 16);
      breg[kk] = __builtin_bit_cast(bf16x8, v);
    }
  }
  // elementwise ownership (waves 0,1): bq=lane&3, cl=lane>>2, jl=w*16+cl
  const int bq = lane & 3;
  const int cl = lane >> 2;
  const int jl = (w & 1) * 16 + cl;
  const int col = nw * 32 + jl;
  const int bno = bg * 4 + bq;
  float c = 0.0f;
  if (w < 2) {
    c = cx[bno * 512 + col];
    asm volatile("" :: "v"(c));
  }

  unsigned int* slot0 = h_tag;
  unsigned int* slot1 = h_tag + 16384;
  const unsigned int* pollp0 = slot0 + bg * 2048 + tid * 4;
  const unsigned int* pollp1 = slot1 + bg * 2048 + tid * 4;
  unsigned int* pub0 = slot0 + bno * 512 + col;
  unsigned int* pub1 = slot1 + bno * 512 + col;
  const unsigned short* gx_base = gx_ws + ((size_t)bg * NCG + nw) * 512;
  const size_t GXT = (size_t)NBG * NCG * 512;
  const size_t BTH = (size_t)B_ * T_ * H_;

  uint4v hv;
  uint4v gxr;
  float pfa = 0.0f, ph = 0.0f, pga = 0.0f;  // deferred out values

  // ---- prologue: gx(0) + slow poll t=0 (tags seeded by prep, remote)
  if (w == 0)
    asm volatile("global_load_dwordx4 %0, %1, off"
                 : "=v"(gxr) : "v"(gx_base + lane * 8));
  {
    POLLS(pollp0);
    VMWAIT(0);
    unsigned bad = (hv[0] >> 16) | (hv[1] >> 16) | (hv[2] >> 16) | (hv[3] >> 16);
    int guard = 0;
    while (bad) {
      POLLS(pollp0);
      VMWAIT(0);
      bad = (hv[0] >> 16) | (hv[1] >> 16) | (hv[2] >> 16) | (hv[3] >> 16);
      if (++guard > (1 << 20)) break;
    }
    uint2v pk;
    pk[0] = (hv[0] & 0xffffu) | (hv[1] << 16);
    pk[1] = (hv[2] & 0xffffu) | (hv[3] << 16);
    *reinterpret_cast<uint2v*>(&As[(tid >> 7) * 536 + (tid & 127) * 4]) = pk;
  }
  if (w == 0)
    *reinterpret_cast<uint4v*>(&GxL[0][lane * 8]) = __builtin_bit_cast(uint4v, gxr);

  for (int t = 0; t < T_; ++t) {
    BARRIER_LGKM();  // A: As + GxL[t&1] ready
    const bool more = (t + 1 < T_);
    // deferred out-stores for step t-1 (age across MFMA + barriers)
    if (w < 2 && t) {
      size_t bo = (size_t)bno * (T_ * H_) + (size_t)(t - 1) * H_ + col;
      asm volatile("global_store_dword %0, %1, off" :: "v"(out + bo), "v"(pfa) : "memory");
      asm volatile("global_store_dword %0, %1, off"
                   :: "v"(out + BTH + bo), "v"(ph) : "memory");
      asm volatile("global_store_dword %0, %1, off"
                   :: "v"(out + 2 * BTH + bo), "v"(pga) : "memory");
    }
    if (w == 0 && more)
      asm volatile("global_load_dwordx4 %0, %1, off"
                   : "=v"(gxr) : "v"(gx_base + (size_t)(t + 1) * GXT + lane * 8));
    // ---- MFMA: full K=512, one N-tile per wave; 2 independent chains
    f32x4 a0 = {}, a1 = {};
#pragma unroll
    for (int kk = 0; kk < 16; kk += 2) {
      bf16x8 af0 = *reinterpret_cast<const bf16x8*>(
          &As[(lane & 3) * 536 + kk * 32 + (lane >> 4) * 8]);
      bf16x8 af1 = *reinterpret_cast<const bf16x8*>(
          &As[(lane & 3) * 536 + (kk + 1) * 32 + (lane >> 4) * 8]);
      a0 = __builtin_amdgcn_mfma_f32_16x16x32_bf16(af0, breg[kk], a0, 0, 0, 0);
      a1 = __builtin_amdgcn_mfma_f32_16x16x32_bf16(af1, breg[kk + 1], a1, 0, 0, 0);
    }
    if (lane < 16) {
      f32x4 s4 = a0 + a1;  // C rows 0-3 = batches 0-3, col = lane
      *reinterpret_cast<f32x4*>(&Gt2[w * 64 + lane * 4]) = s4;
    }
    BARRIER_LGKM();  // B: Gt2 complete; As(t) dead from here
    const unsigned int* pollp = ((t + 1) & 1) ? pollp1 : pollp0;
    if (more && !ownq) POLLF(pollp);  // early fast poll (before publishes)
    if (w < 2) {
      // ---- elementwise (waves 0,1): 128 outputs
      const int gxb = t & 1;
      float s0 = Gt2[(0 * 2 + w) * 64 + lane] + bf2f(GxL[gxb][bq * 128 + 0 * 32 + jl]);
      float s1 = Gt2[(1 * 2 + w) * 64 + lane] + bf2f(GxL[gxb][bq * 128 + 1 * 32 + jl]);
      float s2 = Gt2[(2 * 2 + w) * 64 + lane] + bf2f(GxL[gxb][bq * 128 + 2 * 32 + jl]);
      float s3 = Gt2[(3 * 2 + w) * 64 + lane] + bf2f(GxL[gxb][bq * 128 + 3 * 32 + jl]);
      float ia = sigm(s0), fa = sigm(s1), ga = tanh_(s2), oa = sigm(s3);
      c = fa * c + ia * ga;
      float h = oa * tanh_(c);
      if (more) {
        unsigned short hb = f2bf(h);
        unsigned int word = (unsigned int)hb | (((unsigned int)(t + 1)) << 16);
        unsigned int* q_ = ((t + 1) & 1) ? pub1 : pub0;
        // dual publish: plain (live local L2 line) then sc0sc1 (MALL)
        asm volatile("global_store_dword %0, %1, off" :: "v"(q_), "v"(word) : "memory");
        asm volatile("global_store_dword %0, %1, off sc0 sc1" :: "v"(q_), "v"(word) : "memory");
        As[bq * 536 + col] = hb;  // self-inject own h(t+1) into LDS
        pfa = fa; ph = h; pga = ga;
      } else {
        size_t bo = (size_t)bno * (T_ * H_) + (size_t)t * H_ + col;
        asm volatile("global_store_dword %0, %1, off" :: "v"(out + bo), "v"(fa) : "memory");
        asm volatile("global_store_dword %0, %1, off"
                     :: "v"(out + BTH + bo), "v"(h) : "memory");
        asm volatile("global_store_dword %0, %1, off"
                     :: "v"(out + 2 * BTH + bo), "v"(ga) : "memory");
        out[3 * BTH + (size_t)bno * H_ + col] = oa;
      }
    }
    if (more) {
      // wave FIFO at check:
      //  w==0: [outs3][gxr][pollF][pubL2][pubMALL] -> VMWAIT(2) retires pollF
      //  w==1: [outs3][pollF][pubL2][pubMALL]     -> VMWAIT(2)
      //  w>=2: [pollF]                            -> VMWAIT(0)
      if (w < 2) VMWAIT(2); else VMWAIT(0);
      const unsigned want = (unsigned)(t + 1);
      unsigned bad = 0u;
      if (!ownq)
        bad = ((hv[0] >> 16) ^ want) | ((hv[1] >> 16) ^ want) |
              ((hv[2] >> 16) ^ want) | ((hv[3] >> 16) ^ want);
      int guard = 0;
      while (bad) {
        if (++guard < 4) POLLF(pollp); else POLLS(pollp);
        VMWAIT(0);
        bad = ((hv[0] >> 16) ^ want) | ((hv[1] >> 16) ^ want) |
              ((hv[2] >> 16) ^ want) | ((hv[3] >> 16) ^ want);
        if (guard > (1 << 20)) break;
      }
      if (!ownq) {
        uint2v pk;
        pk[0] = (hv[0] & 0xffffu) | (hv[1] << 16);
        pk[1] = (hv[2] & 0xffffu) | (hv[3] << 16);
        *reinterpret_cast<uint2v*>(&As[(tid >> 7) * 536 + (tid & 127) * 4]) = pk;
      }
      if (w == 0)
        *reinterpret_cast<uint4v*>(&GxL[(t + 1) & 1][lane * 8]) = __builtin_bit_cast(uint4v, gxr);
    }
  }
}

extern "C" void kernel_launch(void* const* d_in, const int* in_sizes, int n_in,
                              void* d_out, int out_size, void* d_ws, size_t ws_size,
                              hipStream_t stream) {
  const float* x    = (const float*)d_in[0];
  const float* hx   = (const float*)d_in[1];
  const float* cx   = (const float*)d_in[2];
  const float* w_ih = (const float*)d_in[3];
  const float* w_hh = (const float*)d_in[4];
  const float* b_ih = (const float*)d_in[5];
  const float* b_hh = (const float*)d_in[6];
  float* out = (float*)d_out;
  char* ws = (char*)d_ws;
  const size_t OFF_XBF  = 0;                    // 67,108,864
  const size_t OFF_WBF  = 67108864;             //  2,097,152
  const size_t OFF_GX   = 69206016;             // 268,435,456
  const size_t OFF_HTAG = 337641472;            //    131,072
  const size_t OFF_CTRL = 337772544;            //      4,096
  const size_t NEEDED   = 337776640;
  if (ws_size < NEEDED) return;

  unsigned short* x_bf  = (unsigned short*)(ws + OFF_XBF);
  unsigned short* w_bf  = (unsigned short*)(ws + OFF_WBF);
  unsigned short* gx_ws = (unsigned short*)(ws + OFF_GX);
  unsigned int*   h_tag = (unsigned int*)(ws + OFF_HTAG);
  unsigned int*   ctrl  = (unsigned int*)(ws + OFF_CTRL);

  prep_kernel<<<16913, 256, 0, stream>>>(x, w_ih, hx, x_bf, w_bf, h_tag, ctrl);
  gemm_gx<<<8192, 256, 0, stream>>>(x_bf, w_bf, b_ih, b_hh, gx_ws);
  lstm_rec<<<128, 512, 0, stream>>>(cx, w_hh, gx_ws, h_tag, ctrl, out);
}

// Round 14
// 3995.887 us; speedup vs baseline: 1.7527x; 1.2468x over previous
//
#include <hip/hip_runtime.h>
#include <stdint.h>

// LSTM forward, B=32 T=2048 D=512 H=512 G=2048.
// Round 14 = r13 + SPLIT exchange buffers:
//   L buffer: published with PLAIN stores only -> line lives DIRTY in the
//     shared per-XCD L2, updated in place each step; co-located consumers'
//     sc0 polls hit it (~250cy). Never touched by sc1 ops (r13 lesson: the
//     same-address sc0sc1 store invalidates the local copy -> MALL misses).
//   M buffer (different cache lines): published with sc0sc1 -> MALL
//     coherence point; fallback polls (after 3 fast tries) read M. Always
//     correct regardless of WG placement.
// Placement: dynamic XCD claim table via s_getreg(HW_REG_XCC_ID) (r13).
// Protocol: tagged dwords (lo16 bf16 h | hi16 step), double-buffered slots,
// tag+payload share a dword => no fences. Stale lines are benign: tags are
// unique within a replay; cross-replay stale values are bit-identical
// (deterministic kernel).

#define B_ 32
#define T_ 2048
#define D_ 512
#define H_ 512
#define G_ 2048
#define NCG 16
#define NBG 8

typedef __attribute__((ext_vector_type(4))) float f32x4;
typedef __attribute__((ext_vector_type(8))) short bf16x8;
typedef __attribute__((ext_vector_type(4))) unsigned int uint4v;
typedef __attribute__((ext_vector_type(2))) unsigned int uint2v;

__device__ __forceinline__ unsigned short f2bf(float f) {
  union { float f; unsigned int u; } v; v.f = f;
  unsigned int r = (v.u + 0x7FFFu + ((v.u >> 16) & 1u)) >> 16;
  return (unsigned short)r;
}
__device__ __forceinline__ float bf2f(unsigned short s) {
  union { unsigned int u; float f; } v; v.u = ((unsigned int)s) << 16;
  return v.f;
}
__device__ __forceinline__ float sigm(float x) { return 1.0f / (1.0f + __expf(-x)); }
__device__ __forceinline__ float tanh_(float x) { return 1.0f - 2.0f / (__expf(2.0f * x) + 1.0f); }

__device__ __forceinline__ void store_x4_coherent(unsigned int* p, uint4v v) {
  asm volatile("global_store_dwordx4 %0, %1, off sc0 sc1" :: "v"(p), "v"(v) : "memory");
}

#define BARRIER_LGKM()                                          \
  do {                                                          \
    asm volatile("s_waitcnt lgkmcnt(0)" ::: "memory");          \
    __builtin_amdgcn_sched_barrier(0);                          \
    __builtin_amdgcn_s_barrier();                               \
    __builtin_amdgcn_sched_barrier(0);                          \
  } while (0)

#define VMWAIT(N)                                               \
  do { asm volatile("s_waitcnt vmcnt(" #N ")" ::: "memory");    \
       __builtin_amdgcn_sched_barrier(0); } while (0)

// ---------------- Phase 1: convert inputs + seed/clear L,M + ctrl ----------
__global__ __launch_bounds__(256) void prep_kernel(
    const float* __restrict__ x, const float* __restrict__ w_ih,
    const float* __restrict__ hx,
    unsigned short* __restrict__ x_bf, unsigned short* __restrict__ w_bf,
    unsigned int* __restrict__ h_tag, unsigned int* __restrict__ ctrl) {
  const int NX8 = (B_ * T_ * D_) / 8;   // 4,194,304
  const int NWT8 = (G_ * D_) / 8;       // 131,072
  const int A = NX8 + NWT8;
  int i = blockIdx.x * 256 + threadIdx.x;
  if (i < NX8) {
    float4 a = reinterpret_cast<const float4*>(x)[i * 2];
    float4 b = reinterpret_cast<const float4*>(x)[i * 2 + 1];
    uint4v v;
    v[0] = (unsigned)f2bf(a.x) | ((unsigned)f2bf(a.y) << 16);
    v[1] = (unsigned)f2bf(a.z) | ((unsigned)f2bf(a.w) << 16);
    v[2] = (unsigned)f2bf(b.x) | ((unsigned)f2bf(b.y) << 16);
    v[3] = (unsigned)f2bf(b.z) | ((unsigned)f2bf(b.w) << 16);
    reinterpret_cast<uint4v*>(x_bf)[i] = v;
  } else if (i < A) {
    int j = i - NX8;
    float4 a = reinterpret_cast<const float4*>(w_ih)[j * 2];
    float4 b = reinterpret_cast<const float4*>(w_ih)[j * 2 + 1];
    uint4v v;
    v[0] = (unsigned)f2bf(a.x) | ((unsigned)f2bf(a.y) << 16);
    v[1] = (unsigned)f2bf(a.z) | ((unsigned)f2bf(a.w) << 16);
    v[2] = (unsigned)f2bf(b.x) | ((unsigned)f2bf(b.y) << 16);
    v[3] = (unsigned)f2bf(b.z) | ((unsigned)f2bf(b.w) << 16);
    reinterpret_cast<uint4v*>(w_bf)[j] = v;
  } else if (i < A + 2048) {
    int j = i - A;  // seed slot 0 from hx, tag 0 (L plain, M sc0sc1)
    float4 a = reinterpret_cast<const float4*>(hx)[j * 2];
    float4 b = reinterpret_cast<const float4*>(hx)[j * 2 + 1];
    uint4v v0, v1;
    v0[0] = f2bf(a.x); v0[1] = f2bf(a.y); v0[2] = f2bf(a.z); v0[3] = f2bf(a.w);
    v1[0] = f2bf(b.x); v1[1] = f2bf(b.y); v1[2] = f2bf(b.z); v1[3] = f2bf(b.w);
    unsigned int* pL = h_tag + j * 8;
    unsigned int* pM = h_tag + 32768 + j * 8;
    *reinterpret_cast<uint4v*>(pL) = v0;
    *reinterpret_cast<uint4v*>(pL + 4) = v1;
    store_x4_coherent(pM, v0);
    store_x4_coherent(pM + 4, v1);
  } else if (i < A + 4096) {
    int j = i - A - 2048;  // clear slot 1 (L plain, M sc0sc1)
    unsigned int* pL = h_tag + 16384 + j * 8;
    unsigned int* pM = h_tag + 49152 + j * 8;
    uint4v z = {0u, 0u, 0u, 0u};
    *reinterpret_cast<uint4v*>(pL) = z;
    *reinterpret_cast<uint4v*>(pL + 4) = z;
    store_x4_coherent(pM, z);
    store_x4_coherent(pM + 4, z);
  } else {
    int j = i - A - 4096;  // clear ctrl (counters + claim table), 256 dwords
    unsigned int* p = ctrl + j;
    unsigned int z = 0u;
    asm volatile("global_store_dword %0, %1, off sc0 sc1" :: "v"(p), "v"(z) : "memory");
  }
}

// ---------------- Phase 2: gx GEMM (r12 layout, NCG=16) ----------------
__global__ __launch_bounds__(256, 2) void gemm_gx(
    const unsigned short* __restrict__ x_bf, const unsigned short* __restrict__ w_bf,
    const float* __restrict__ b_ih, const float* __restrict__ b_hh,
    unsigned short* __restrict__ gx_ws) {
  __shared__ unsigned short As[128 * 40];
  __shared__ unsigned short Bs[128 * 40];
  __shared__ unsigned short Eg[128 * 136];
  const int bid = blockIdx.x;
  const int cb = bid & 15, rb = bid >> 4;
  const int r0 = rb * 128, c0 = cb * 128;
  const int tid = threadIdx.x;
  const int lane = tid & 63;
  const int w = tid >> 6;
  const int qr = (w >> 1) * 64, qc = (w & 1) * 64;
  f32x4 acc[4][4] = {};

  for (int kt = 0; kt < 16; ++kt) {
    const int k0 = kt * 32;
    uint4v av[2], bv[2];
#pragma unroll
    for (int c = 0; c < 2; ++c) {
      int flat = c * 256 + tid;
      int row = flat >> 2, q = flat & 3;
      av[c] = *reinterpret_cast<const uint4v*>(x_bf + (size_t)(r0 + row) * 512 + k0 + q * 8);
      bv[c] = *reinterpret_cast<const uint4v*>(w_bf + (size_t)(c0 + row) * 512 + k0 + q * 8);
    }
    __syncthreads();
#pragma unroll
    for (int c = 0; c < 2; ++c) {
      int flat = c * 256 + tid;
      int row = flat >> 2, q = flat & 3;
      *reinterpret_cast<uint4v*>(&As[row * 40 + q * 8]) = av[c];
      *reinterpret_cast<uint4v*>(&Bs[row * 40 + q * 8]) = bv[c];
    }
    __syncthreads();
    bf16x8 af[4], bfr[4];
#pragma unroll
    for (int mt = 0; mt < 4; ++mt)
      af[mt] = *reinterpret_cast<const bf16x8*>(&As[(qr + mt * 16 + (lane & 15)) * 40 + (lane >> 4) * 8]);
#pragma unroll
    for (int nt = 0; nt < 4; ++nt)
      bfr[nt] = *reinterpret_cast<const bf16x8*>(&Bs[(qc + nt * 16 + (lane & 15)) * 40 + (lane >> 4) * 8]);
#pragma unroll
    for (int mt = 0; mt < 4; ++mt)
#pragma unroll
      for (int nt = 0; nt < 4; ++nt)
        acc[mt][nt] = __builtin_amdgcn_mfma_f32_16x16x32_bf16(af[mt], bfr[nt], acc[mt][nt], 0, 0, 0);
  }
  __syncthreads();
#pragma unroll
  for (int nt = 0; nt < 4; ++nt) {
    int cg = c0 + qc + nt * 16 + (lane & 15);
    float bias = b_ih[cg] + b_hh[cg];
#pragma unroll
    for (int mt = 0; mt < 4; ++mt)
#pragma unroll
      for (int j = 0; j < 4; ++j) {
        int tr = qr + mt * 16 + (lane >> 4) * 4 + j;
        int cl = qc + nt * 16 + (lane & 15);
        Eg[tr * 136 + cl] = f2bf(acc[mt][nt][j] + bias);
      }
  }
  __syncthreads();
  const int b = r0 >> 11;
  const int g = c0 >> 9;
  const int t0 = r0 & 2047;
  const int nw0 = (c0 & 511) >> 5;
  const int bg = b >> 2, bq = b & 3;
  for (int c = tid; c < 512; c += 256) {
    int tr = c >> 2, nwi = c & 3;
    size_t dst = (((size_t)(t0 + tr) * NBG + bg) * NCG + (nw0 + nwi)) * 512 + bq * 128 + g * 32;
    const unsigned short* src = &Eg[tr * 136 + nwi * 32];
#pragma unroll
    for (int q = 0; q < 4; ++q)
      *reinterpret_cast<uint4v*>(gx_ws + dst + q * 8) =
          *reinterpret_cast<const uint4v*>(src + q * 8);
  }
}

// ---------------- Phase 3: recurrence ----------------
#define POLLF(PP) \
  asm volatile("global_load_dwordx4 %0, %1, off sc0" : "=v"(hv) : "v"(PP))
#define POLLS(PP) \
  asm volatile("global_load_dwordx4 %0, %1, off sc0 sc1" : "=v"(hv) : "v"(PP))

__global__ __launch_bounds__(512) void lstm_rec(
    const float* __restrict__ cx, const float* __restrict__ w_hh,
    const unsigned short* __restrict__ gx_ws, unsigned int* __restrict__ h_tag,
    unsigned int* __restrict__ ctrl, float* __restrict__ out) {
  const int tid = threadIdx.x;
  const int lane = tid & 63;
  const int w = tid >> 6;
  __shared__ unsigned short As[4 * 536];   // h rows (bf16), stride 536
  __shared__ float Gt2[8 * 64];            // [tile n][cl*4+bq]
  __shared__ unsigned short GxL[2][512];   // gx dbuf [bq][g][jl]
  __shared__ int sdr[2];

  // ---- dynamic XCD-grouped slot claim: domain = this WG's real XCD ----
  if (tid == 0) {
    int xcd;
    asm volatile("s_getreg_b32 %0, hwreg(HW_REG_XCC_ID)" : "=s"(xcd));
    xcd &= 7;
    unsigned int* cnt = ctrl;        // [8] per-XCD counters
    unsigned int* clm = ctrl + 8;    // [128] claim flags
    int slot = -1;
    unsigned role = atomicAdd(&cnt[xcd], 1u);
    if (role < 16u) {
      if (atomicCAS(&clm[xcd * 16 + role], 0u, 1u) == 0u)
        slot = xcd * 16 + (int)role;
    }
    while (slot < 0) {               // overflow: steal any free slot
      for (int s = 0; s < 128 && slot < 0; ++s)
        if (atomicCAS(&clm[s], 0u, 1u) == 0u) slot = s;
    }
    sdr[0] = slot >> 4;   // bg (domain == XCD when balanced)
    sdr[1] = slot & 15;   // nw (col-group)
  }
  __syncthreads();
  const int bg = sdr[0];
  const int nw = sdr[1];
  const int gi = w >> 1;
  const int half = w & 1;
  const bool ownq = (((tid & 127) >> 3) == nw);  // poll dwords are own cols

  // B-frags: one N-tile (16 gate-cols), full K=512 -> 16 frags = 64 VGPR
  bf16x8 breg[16];
  {
    int gcol = gi * 512 + nw * 32 + half * 16 + (lane & 15);
    const float* wrow = w_hh + (size_t)gcol * 512;
#pragma unroll
    for (int kk = 0; kk < 16; ++kk) {
      int k = kk * 32 + (lane >> 4) * 8;
      float4 f0 = *reinterpret_cast<const float4*>(wrow + k);
      float4 f1 = *reinterpret_cast<const float4*>(wrow + k + 4);
      uint4v v;
      v[0] = (unsigned)f2bf(f0.x) | ((unsigned)f2bf(f0.y) << 16);
      v[1] = (unsigned)f2bf(f0.z) | ((unsigned)f2bf(f0.w) << 16);
      v[2] = (unsigned)f2bf(f1.x) | ((unsigned)f2bf(f1.y) << 16);
      v[3] = (unsigned)f2bf(f1.z) | ((unsigned)f2bf(f1.w) << 16);
      breg[kk] = __builtin_bit_cast(bf16x8, v);
    }
  }
  // elementwise ownership (waves 0,1): bq=lane&3, cl=lane>>2, jl=w*16+cl
  const int bq = lane & 3;
  const int cl = lane >> 2;
  const int jl = (w & 1) * 16 + cl;
  const int col = nw * 32 + jl;
  const int bno = bg * 4 + bq;
  float c = 0.0f;
  if (w < 2) {
    c = cx[bno * 512 + col];
    asm volatile("" :: "v"(c));
  }

  // L buffer (local, plain): slots at 0 / 16384. M buffer (MALL, sc0sc1):
  // slots at 32768 / 49152. Different cache lines.
  const unsigned int* pollL0 = h_tag + bg * 2048 + tid * 4;
  const unsigned int* pollL1 = pollL0 + 16384;
  const unsigned int* pollM0 = pollL0 + 32768;
  const unsigned int* pollM1 = pollL0 + 49152;
  unsigned int* pubL0 = h_tag + bno * 512 + col;
  unsigned int* pubL1 = pubL0 + 16384;
  unsigned int* pubM0 = pubL0 + 32768;
  unsigned int* pubM1 = pubL0 + 49152;
  const unsigned short* gx_base = gx_ws + ((size_t)bg * NCG + nw) * 512;
  const size_t GXT = (size_t)NBG * NCG * 512;
  const size_t BTH = (size_t)B_ * T_ * H_;

  uint4v hv;
  uint4v gxr;
  float pfa = 0.0f, ph = 0.0f, pga = 0.0f;  // deferred out values

  // ---- prologue: gx(0) + slow poll t=0 on M (seeded sc0sc1, remote)
  if (w == 0)
    asm volatile("global_load_dwordx4 %0, %1, off"
                 : "=v"(gxr) : "v"(gx_base + lane * 8));
  {
    POLLS(pollM0);
    VMWAIT(0);
    unsigned bad = (hv[0] >> 16) | (hv[1] >> 16) | (hv[2] >> 16) | (hv[3] >> 16);
    int guard = 0;
    while (bad) {
      POLLS(pollM0);
      VMWAIT(0);
      bad = (hv[0] >> 16) | (hv[1] >> 16) | (hv[2] >> 16) | (hv[3] >> 16);
      if (++guard > (1 << 20)) break;
    }
    uint2v pk;
    pk[0] = (hv[0] & 0xffffu) | (hv[1] << 16);
    pk[1] = (hv[2] & 0xffffu) | (hv[3] << 16);
    *reinterpret_cast<uint2v*>(&As[(tid >> 7) * 536 + (tid & 127) * 4]) = pk;
  }
  if (w == 0)
    *reinterpret_cast<uint4v*>(&GxL[0][lane * 8]) = __builtin_bit_cast(uint4v, gxr);

  for (int t = 0; t < T_; ++t) {
    BARRIER_LGKM();  // A: As + GxL[t&1] ready
    const bool more = (t + 1 < T_);
    // deferred out-stores for step t-1 (age across MFMA + barriers)
    if (w < 2 && t) {
      size_t bo = (size_t)bno * (T_ * H_) + (size_t)(t - 1) * H_ + col;
      asm volatile("global_store_dword %0, %1, off" :: "v"(out + bo), "v"(pfa) : "memory");
      asm volatile("global_store_dword %0, %1, off"
                   :: "v"(out + BTH + bo), "v"(ph) : "memory");
      asm volatile("global_store_dword %0, %1, off"
                   :: "v"(out + 2 * BTH + bo), "v"(pga) : "memory");
    }
    if (w == 0 && more)
      asm volatile("global_load_dwordx4 %0, %1, off"
                   : "=v"(gxr) : "v"(gx_base + (size_t)(t + 1) * GXT + lane * 8));
    // ---- MFMA: full K=512, one N-tile per wave; 2 independent chains
    f32x4 a0 = {}, a1 = {};
#pragma unroll
    for (int kk = 0; kk < 16; kk += 2) {
      bf16x8 af0 = *reinterpret_cast<const bf16x8*>(
          &As[(lane & 3) * 536 + kk * 32 + (lane >> 4) * 8]);
      bf16x8 af1 = *reinterpret_cast<const bf16x8*>(
          &As[(lane & 3) * 536 + (kk + 1) * 32 + (lane >> 4) * 8]);
      a0 = __builtin_amdgcn_mfma_f32_16x16x32_bf16(af0, breg[kk], a0, 0, 0, 0);
      a1 = __builtin_amdgcn_mfma_f32_16x16x32_bf16(af1, breg[kk + 1], a1, 0, 0, 0);
    }
    if (lane < 16) {
      f32x4 s4 = a0 + a1;  // C rows 0-3 = batches 0-3, col = lane
      *reinterpret_cast<f32x4*>(&Gt2[w * 64 + lane * 4]) = s4;
    }
    BARRIER_LGKM();  // B: Gt2 complete; As(t) dead from here
    const unsigned int* pollL = ((t + 1) & 1) ? pollL1 : pollL0;
    const unsigned int* pollM = ((t + 1) & 1) ? pollM1 : pollM0;
    if (more && !ownq) POLLF(pollL);  // early fast poll (L, local L2)
    if (w < 2) {
      // ---- elementwise (waves 0,1): 128 outputs
      const int gxb = t & 1;
      float s0 = Gt2[(0 * 2 + w) * 64 + lane] + bf2f(GxL[gxb][bq * 128 + 0 * 32 + jl]);
      float s1 = Gt2[(1 * 2 + w) * 64 + lane] + bf2f(GxL[gxb][bq * 128 + 1 * 32 + jl]);
      float s2 = Gt2[(2 * 2 + w) * 64 + lane] + bf2f(GxL[gxb][bq * 128 + 2 * 32 + jl]);
      float s3 = Gt2[(3 * 2 + w) * 64 + lane] + bf2f(GxL[gxb][bq * 128 + 3 * 32 + jl]);
      float ia = sigm(s0), fa = sigm(s1), ga = tanh_(s2), oa = sigm(s3);
      c = fa * c + ia * ga;
      float h = oa * tanh_(c);
      if (more) {
        unsigned short hb = f2bf(h);
        unsigned int word = (unsigned int)hb | (((unsigned int)(t + 1)) << 16);
        unsigned int* qL = ((t + 1) & 1) ? pubL1 : pubL0;
        unsigned int* qM = ((t + 1) & 1) ? pubM1 : pubM0;
        // L: plain (stays dirty+live in shared local L2; sc0 polls hit it)
        asm volatile("global_store_dword %0, %1, off" :: "v"(qL), "v"(word) : "memory");
        // M: sc0sc1 (MALL mirror, correctness for misplaced WGs)
        asm volatile("global_store_dword %0, %1, off sc0 sc1" :: "v"(qM), "v"(word) : "memory");
        As[bq * 536 + col] = hb;  // self-inject own h(t+1) into LDS
        pfa = fa; ph = h; pga = ga;
      } else {
        size_t bo = (size_t)bno * (T_ * H_) + (size_t)t * H_ + col;
        asm volatile("global_store_dword %0, %1, off" :: "v"(out + bo), "v"(fa) : "memory");
        asm volatile("global_store_dword %0, %1, off"
                     :: "v"(out + BTH + bo), "v"(h) : "memory");
        asm volatile("global_store_dword %0, %1, off"
                     :: "v"(out + 2 * BTH + bo), "v"(ga) : "memory");
        out[3 * BTH + (size_t)bno * H_ + col] = oa;
      }
    }
    if (more) {
      // wave FIFO at check:
      //  w==0: [outs3][gxr][pollF][pubL][pubM] -> VMWAIT(2) retires pollF+gxr
      //  w==1: [outs3][pollF][pubL][pubM]      -> VMWAIT(2)
      //  w>=2: [pollF]                         -> VMWAIT(0)
      if (w < 2) VMWAIT(2); else VMWAIT(0);
      const unsigned want = (unsigned)(t + 1);
      unsigned bad = 0u;
      if (!ownq)
        bad = ((hv[0] >> 16) ^ want) | ((hv[1] >> 16) ^ want) |
              ((hv[2] >> 16) ^ want) | ((hv[3] >> 16) ^ want);
      int guard = 0;
      while (bad) {
        if (++guard < 4) POLLF(pollL); else POLLS(pollM);
        VMWAIT(0);
        bad = ((hv[0] >> 16) ^ want) | ((hv[1] >> 16) ^ want) |
              ((hv[2] >> 16) ^ want) | ((hv[3] >> 16) ^ want);
        if (guard > (1 << 20)) break;
      }
      if (!ownq) {
        uint2v pk;
        pk[0] = (hv[0] & 0xffffu) | (hv[1] << 16);
        pk[1] = (hv[2] & 0xffffu) | (hv[3] << 16);
        *reinterpret_cast<uint2v*>(&As[(tid >> 7) * 536 + (tid & 127) * 4]) = pk;
      }
      if (w == 0)
        *reinterpret_cast<uint4v*>(&GxL[(t + 1) & 1][lane * 8]) = __builtin_bit_cast(uint4v, gxr);
    }
  }
}

extern "C" void kernel_launch(void* const* d_in, const int* in_sizes, int n_in,
                              void* d_out, int out_size, void* d_ws, size_t ws_size,
                              hipStream_t stream) {
  const float* x    = (const float*)d_in[0];
  const float* hx   = (const float*)d_in[1];
  const float* cx   = (const float*)d_in[2];
  const float* w_ih = (const float*)d_in[3];
  const float* w_hh = (const float*)d_in[4];
  const float* b_ih = (const float*)d_in[5];
  const float* b_hh = (const float*)d_in[6];
  float* out = (float*)d_out;
  char* ws = (char*)d_ws;
  const size_t OFF_XBF  = 0;                    // 67,108,864
  const size_t OFF_WBF  = 67108864;             //  2,097,152
  const size_t OFF_GX   = 69206016;             // 268,435,456
  const size_t OFF_HTAG = 337641472;            //    262,144 (L + M)
  const size_t OFF_CTRL = 337903616;            //      4,096
  const size_t NEEDED   = 337907712;
  if (ws_size < NEEDED) return;

  unsigned short* x_bf  = (unsigned short*)(ws + OFF_XBF);
  unsigned short* w_bf  = (unsigned short*)(ws + OFF_WBF);
  unsigned short* gx_ws = (unsigned short*)(ws + OFF_GX);
  unsigned int*   h_tag = (unsigned int*)(ws + OFF_HTAG);
  unsigned int*   ctrl  = (unsigned int*)(ws + OFF_CTRL);

  prep_kernel<<<16913, 256, 0, stream>>>(x, w_ih, hx, x_bf, w_bf, h_tag, ctrl);
  gemm_gx<<<8192, 256, 0, stream>>>(x_bf, w_bf, b_ih, b_hh, gx_ws);
  lstm_rec<<<128, 512, 0, stream>>>(cx, w_hh, gx_ws, h_tag, ctrl, out);
}